// Round 7
// baseline (749.610 us; speedup 1.0000x reference)
//
#include <hip/hip_runtime.h>
#include <hip/hip_bf16.h>

#define NN 50000
#define NE 800000
#define EPSV 1e-5f
#define NB 49   // scan blocks: ceil(NN/1024)

typedef _Float16 h8 __attribute__((ext_vector_type(8)));
typedef _Float16 h2 __attribute__((ext_vector_type(2)));
typedef float    f4 __attribute__((ext_vector_type(4)));

#define AS1 __attribute__((address_space(1)))
#define AS3 __attribute__((address_space(3)))

__device__ __forceinline__ void gload_lds16(const _Float16* g, _Float16* l){
  __builtin_amdgcn_global_load_lds((const AS1 void*)g, (AS3 void*)l, 16, 0, 0);
}

// ---------------- graph preprocessing ----------------

__global__ void k_deg(const int* __restrict__ dst, int* __restrict__ deg){
  int e = blockIdx.x*blockDim.x + threadIdx.x;
  if(e < NE) atomicAdd(&deg[dst[e]], 1);
}

__global__ void k_logdeg(const int* __restrict__ deg, float* __restrict__ logdeg,
                         float* __restrict__ dsum){
  int i = blockIdx.x*blockDim.x + threadIdx.x;
  float v = 0.f;
  if(i < NN){ v = log1pf((float)deg[i]); logdeg[i] = v; }
  __shared__ float sh[256];
  sh[threadIdx.x] = v; __syncthreads();
  for(int off=128; off>0; off>>=1){
    if(threadIdx.x < off) sh[threadIdx.x] += sh[threadIdx.x+off];
    __syncthreads();
  }
  if(threadIdx.x == 0) atomicAdd(dsum, sh[0]);
}

__global__ void k_scalers(const float* __restrict__ logdeg, const float* __restrict__ dsum,
                          float* __restrict__ amp, float* __restrict__ att){
  int i = blockIdx.x*blockDim.x + threadIdx.x;
  if(i >= NN) return;
  float delta = dsum[0] / (float)NN;
  float ld = logdeg[i];
  amp[i] = ld / delta;
  att[i] = (ld > 0.f) ? (delta / fmaxf(ld, 1e-6f)) : 1.f;
}

// 3-phase parallel exclusive scan of deg -> rowptr (+cursor copy)
__global__ void k_scan1(const int* __restrict__ deg, int* __restrict__ rowptr,
                        int* __restrict__ bsum){
  __shared__ int buf[1024];
  int tid = threadIdx.x;
  int i = blockIdx.x*1024 + tid;
  int v = (i < NN) ? deg[i] : 0;
  buf[tid] = v; __syncthreads();
  for(int off=1; off<1024; off<<=1){
    int t = (tid >= off) ? buf[tid-off] : 0;
    __syncthreads();
    buf[tid] += t;
    __syncthreads();
  }
  if(i < NN) rowptr[i] = buf[tid] - v;
  if(tid == 1023) bsum[blockIdx.x] = buf[1023];
}

__global__ void k_scan2(int* __restrict__ bsum){
  if(threadIdx.x == 0){
    int s = 0;
    for(int b = 0; b < NB; b++){ int t = bsum[b]; bsum[b] = s; s += t; }
    bsum[NB] = s;
  }
}

__global__ void k_scan3(int* __restrict__ rowptr, int* __restrict__ cursor,
                        const int* __restrict__ bsum){
  int i = blockIdx.x*256 + threadIdx.x;
  if(i < NN){
    int v = rowptr[i] + bsum[i >> 10];
    rowptr[i] = v; cursor[i] = v;
  }
  if(i == NN) rowptr[NN] = bsum[NB];
}

__global__ void k_fill(const int* __restrict__ src, const int* __restrict__ dst,
                       int* __restrict__ cursor, int* __restrict__ colidx){
  int e = blockIdx.x*blockDim.x + threadIdx.x;
  if(e < NE){
    int pos = atomicAdd(&cursor[dst[e]], 1);
    colidx[pos] = src[e];
  }
}

__global__ void k_cvtx(const float* __restrict__ x, _Float16* __restrict__ act){
  int i = blockIdx.x*256 + threadIdx.x;
  if(i < NN*64) act[i] = (_Float16)x[i];
}

// identity BN coefficients for layer 1
__global__ void k_coef_id(float* __restrict__ cs, float* __restrict__ csh,
                          _Float16* __restrict__ cs16, _Float16* __restrict__ csh16){
  int c = threadIdx.x;
  cs[c] = 1.f; csh[c] = 0.f;
  cs16[c] = (_Float16)1.f; csh16[c] = (_Float16)0.f;
}

// BN coefficients from stats: v' = a*v + b with a=inv*gamma, b=beta-mean*a
__global__ void k_bn_coef(const float* __restrict__ colsum, const float* __restrict__ colss,
                          const float* __restrict__ gamma, const float* __restrict__ beta,
                          int dout, float* __restrict__ cs, float* __restrict__ csh,
                          _Float16* __restrict__ cs16, _Float16* __restrict__ csh16){
  int c = threadIdx.x;
  if(c >= dout) return;
  float mean = colsum[c] / (float)NN;
  float var  = colss[c] / (float)NN - mean*mean;
  float inv  = rsqrtf(fmaxf(var, 0.f) + EPSV);
  float a = inv * gamma[c];
  float b = beta[c] - mean * a;
  cs[c] = a; csh[c] = b;
  cs16[c] = (_Float16)a; csh16[c] = (_Float16)b;
}

// ---------------- aggregation: 2-team edge-split, mix-fma/packed VALU ----------
// VALU diet (kernel was 81% VALUBusy): sum/sumsq accumulate via
// fmaf((float)h, ., .) which the backend folds to v_fma_mix_f32 (f16 src, no
// cvt); min/max stay packed h2 via v_pk_min/max_f16. 24 VALU ops per
// 8-element fragment vs 40 for cvt+add+fma+min+max. Bit-identical results.

template<int D>
__global__ __launch_bounds__(256) void k_agg2t(
    const _Float16* __restrict__ act,
    const int* __restrict__ rowptr, const int* __restrict__ colidx,
    const float* __restrict__ cs, const float* __restrict__ csh,
    _Float16* __restrict__ aggs, size_t aggN)
{
  constexpr int CL  = D >> 3;       // col-lanes per team: 8/16/32
  constexpr int LPN = CL * 2;       // lanes per node (2 teams)
  constexpr int NPW = 64 / LPN;     // nodes per wave: 4/2/1
  int wv = threadIdx.x >> 6, lane = threadIdx.x & 63;
  int n = blockIdx.x*(NPW*4) + wv*NPW + (lane / LPN);
  int team = (lane / CL) & 1;
  int c = (lane % CL) * 8;          // 8 adjacent feature cols
  if(n >= NN) return;
  int beg = rowptr[n], end = rowptr[n+1];
  int deg = end - beg;
  int half1 = (deg + 1) >> 1;
  int tb = team ? (beg + half1) : beg;
  int te = team ? end : (beg + half1);
  const _Float16* hp = act + c;

  float s[8], q[8];
  h2 mnh[4], mxh[4];
  #pragma unroll
  for(int j = 0; j < 8; j++){ s[j]=0.f; q[j]=0.f; }
  #pragma unroll
  for(int p = 0; p < 4; p++){
    mnh[p] = h2{(_Float16)INFINITY, (_Float16)INFINITY};
    mxh[p] = h2{(_Float16)(-INFINITY), (_Float16)(-INFINITY)};
  }

#define ACC8(v) { \
  _Pragma("unroll") for(int j=0;j<8;j++){ \
    float a_ = (float)(v)[j]; \
    s[j] = fmaf(a_, 1.0f, s[j]); \
    q[j] = fmaf(a_, a_, q[j]); \
  } \
  _Pragma("unroll") for(int p=0;p<4;p++){ \
    h2 pr_ = h2{(v)[2*p], (v)[2*p+1]}; \
    mnh[p] = __builtin_elementwise_min(mnh[p], pr_); \
    mxh[p] = __builtin_elementwise_max(mxh[p], pr_); \
  } \
}

  int e = tb;
  for(; e+8 <= te; e+=8){
    int i0=colidx[e],   i1=colidx[e+1], i2=colidx[e+2], i3=colidx[e+3];
    int i4=colidx[e+4], i5=colidx[e+5], i6=colidx[e+6], i7=colidx[e+7];
    h8 v0 = *(const h8*)(hp + (size_t)i0*D);
    h8 v1 = *(const h8*)(hp + (size_t)i1*D);
    h8 v2 = *(const h8*)(hp + (size_t)i2*D);
    h8 v3 = *(const h8*)(hp + (size_t)i3*D);
    h8 v4 = *(const h8*)(hp + (size_t)i4*D);
    h8 v5 = *(const h8*)(hp + (size_t)i5*D);
    h8 v6 = *(const h8*)(hp + (size_t)i6*D);
    h8 v7 = *(const h8*)(hp + (size_t)i7*D);
    ACC8(v0) ACC8(v1) ACC8(v2) ACC8(v3) ACC8(v4) ACC8(v5) ACC8(v6) ACC8(v7)
  }
  for(; e+4 <= te; e+=4){
    int i0=colidx[e], i1=colidx[e+1], i2=colidx[e+2], i3=colidx[e+3];
    h8 v0 = *(const h8*)(hp + (size_t)i0*D);
    h8 v1 = *(const h8*)(hp + (size_t)i1*D);
    h8 v2 = *(const h8*)(hp + (size_t)i2*D);
    h8 v3 = *(const h8*)(hp + (size_t)i3*D);
    ACC8(v0) ACC8(v1) ACC8(v2) ACC8(v3)
  }
  for(; e < te; e++){
    h8 v = *(const h8*)(hp + (size_t)colidx[e]*D);
    ACC8(v)
  }
#undef ACC8

  // combine teams: partner lane differs only in the team bit (same node)
  #pragma unroll
  for(int j = 0; j < 8; j++){
    s[j] += __shfl_xor(s[j], CL);
    q[j] += __shfl_xor(q[j], CL);
  }
  #pragma unroll
  for(int p = 0; p < 4; p++){
    int bn = __shfl_xor(__builtin_bit_cast(int, mnh[p]), CL);
    int bx = __shfl_xor(__builtin_bit_cast(int, mxh[p]), CL);
    mnh[p] = __builtin_elementwise_min(mnh[p], __builtin_bit_cast(h2, bn));
    mxh[p] = __builtin_elementwise_max(mxh[p], __builtin_bit_cast(h2, bx));
  }
  if(team) return;                  // team 0 writes the result

  float cnt = (deg > 0) ? (float)deg : 1.f;
  h8 vm, vn, vx, vs;
  #pragma unroll
  for(int j = 0; j < 8; j++){
    float a = cs[c+j], b = csh[c+j];
    float mnv = (float)mnh[j>>1][j&1];
    float mxv = (float)mxh[j>>1][j&1];
    float mean_r = s[j]/cnt;
    float var_r  = fmaxf(q[j]/cnt - mean_r*mean_r, 0.f);
    float meanp = a*mean_r + b;
    float mnp = (a >= 0.f) ? a*mnv+b : a*mxv+b;
    float mxp = (a >= 0.f) ? a*mxv+b : a*mnv+b;
    float sdp = sqrtf(a*a*var_r + EPSV);
    if(deg <= 0){ meanp = 0.f; mnp = 0.f; mxp = 0.f; sdp = sqrtf(EPSV); }
    vm[j] = (_Float16)meanp; vn[j] = (_Float16)mnp;
    vx[j] = (_Float16)mxp;   vs[j] = (_Float16)sdp;
  }

  _Float16* dst = aggs + (size_t)(c>>6)*aggN + (size_t)n*256 + (c & 63);
  *(h8*)(dst)       = vm;
  *(h8*)(dst + 64)  = vn;
  *(h8*)(dst + 128) = vx;
  *(h8*)(dst + 192) = vs;
}

// ---------------- fused W pre-pack (all layers/chunks, one kernel) ----------------

struct PackJob { const float* W; _Float16* dst; int d, o, j0, start; };
struct PackArgs { PackJob job[9]; int total; };

__global__ void k_pack_all(PackArgs a){
  int idx = blockIdx.x*256 + threadIdx.x;
  if(idx >= a.total) return;
  int ji = 0;
  while(ji < 8 && idx >= a.job[ji+1].start) ji++;
  PackJob J = a.job[ji];
  int rel = idx - J.start;
  int j    = rel & 7;
  int lane = (rel >> 3) & 63;
  int rem  = rel >> 9;
  int ntiles = J.o >> 4;
  int kb = rem / ntiles;
  int nt = rem - kb*ntiles;
  int k = kb*32 + (lane>>4)*8 + j;
  int n = nt*16 + (lane&15);
  int srcrow;
  if(k < 64)       srcrow = J.j0 + k;
  else if(k < 320){ int t=k-64;  srcrow = (1+(t>>6))*J.d + J.j0 + (t&63); }
  else if(k < 576){ int t=k-320; srcrow = (5+(t>>6))*J.d + J.j0 + (t&63); }
  else            { int t=k-576; srcrow = (9+(t>>6))*J.d + J.j0 + (t&63); }
  J.dst[rel] = (_Float16)J.W[(size_t)srcrow*J.o + n];
}

// ---------------- fused MFMA layer GEMM: counted-vmcnt pipelined phases --------
// (r2-exact, known-good 97 us) Per phase p: copy A(p) from bank, issue
// B-stage(p+1) via global_load_lds, sched_barrier pin, issue A-prefetch(p+2),
// MFMA cluster (setprio), then "s_waitcnt vmcnt(K); s_barrier".

template<int NCH>
__global__ __launch_bounds__(256) void k_mfma_fused(
    const _Float16* __restrict__ actIn,
    const _Float16* __restrict__ aggs,          // [NCH][NN][256]
    const float* __restrict__ amp, const float* __restrict__ att,
    const _Float16* __restrict__ cs16, const _Float16* __restrict__ csh16,
    const _Float16* __restrict__ Wp, int o,     // [NCH][832*o]
    const float* __restrict__ bias,
    _Float16* __restrict__ out,                 // [NN][o], relu'd pre-BN
    float* __restrict__ colsum, float* __restrict__ colss,
    size_t aggN)
{
  constexpr int D = NCH * 64;
  constexpr int NPH = NCH * 9;
  __shared__ _Float16 Bsm[2][12*512];           // 2 x 12 KB double buffer
  __shared__ float redS[64], redQ[64];
  int tid  = threadIdx.x;
  int wv   = tid >> 6;
  int lane = tid & 63;
  int mi   = lane & 15;
  int q    = lane >> 4;

  // bijective XCD swizzle (m204): same-y blocks land on same XCD's L2
  int T  = gridDim.x * gridDim.y;
  int n_ = blockIdx.y * gridDim.x + blockIdx.x;
  int qq = T >> 3, rr = T & 7, xc = n_ & 7, nl = n_ >> 3;
  int m_ = (xc < rr ? xc*(qq+1) : rr*(qq+1) + (xc-rr)*qq) + nl;
  int bx = m_ % gridDim.x;
  int by = m_ / gridDim.x;

  int m0   = by * 128 + wv * 32;
  int c0   = bx * 64;
  int ntiles = o >> 4;
  int nt0  = bx * 4;

  if(tid < 64){ redS[tid] = 0.f; redQ[tid] = 0.f; }

  int mrow[2];
  mrow[0] = min(m0 + mi,      NN-1);
  mrow[1] = min(m0 + 16 + mi, NN-1);
  _Float16 am16[2] = { (_Float16)amp[mrow[0]], (_Float16)amp[mrow[1]] };
  _Float16 at16[2] = { (_Float16)att[mrow[0]], (_Float16)att[mrow[1]] };
  const _Float16* hAb[2];
  const _Float16* agb[2];
  hAb[0] = actIn + (size_t)mrow[0]*D + q*8;
  hAb[1] = actIn + (size_t)mrow[1]*D + q*8;
  agb[0] = aggs + (size_t)mrow[0]*256 + q*8;
  agb[1] = aggs + (size_t)mrow[1]*256 + q*8;

  f4 acc[2][4] = {};

  // B-tile staging: tile ti lives at buf[ti*512 + lane*8]
  auto stageX = [&](_Float16* buf, int c){
    const _Float16* Wpc = Wp + (size_t)c*832*o;
    #pragma unroll
    for(int s = 0; s < 2; s++){
      int ti = wv*2 + s;
      int kb = ti >> 2, nn = ti & 3;
      gload_lds16(Wpc + (((size_t)kb*ntiles + nt0 + nn)*64 + lane)*8,
                  buf + ti*512);
    }
  };
  auto stageP = [&](_Float16* buf, int c, int idx){
    const _Float16* Wpc = Wp + (size_t)c*832*o;
    #pragma unroll
    for(int s = 0; s < 3; s++){
      int ti = wv*3 + s;
      int kj = ti >> 2, nn = ti & 3;
      int kb = (kj == 0 ? 2 : (kj == 1 ? 10 : 18)) + idx;
      gload_lds16(Wpc + (((size_t)kb*ntiles + nt0 + nn)*64 + lane)*8,
                  buf + ti*512);
    }
  };

  // A-prefetch register banks (2-phase lead, statically indexed after unroll)
  h8 pA[2][4]; h8 pS[2][2]; h8 pH[2][2];
  auto loadA = [&](int ph2, int bank){
    if(ph2 >= NPH) return;
    int c = ph2 / 9, sub = ph2 % 9;
    if(sub == 0){
      #pragma unroll
      for(int kb = 0; kb < 2; kb++){
        pS[bank][kb] = *(const h8*)(cs16  + c*64 + kb*32 + q*8);
        pH[bank][kb] = *(const h8*)(csh16 + c*64 + kb*32 + q*8);
        #pragma unroll
        for(int t = 0; t < 2; t++)
          pA[bank][kb*2+t] = *(const h8*)(hAb[t] + c*64 + kb*32);
      }
    } else {
      int idx = sub - 1;
      #pragma unroll
      for(int t = 0; t < 2; t++)
        pA[bank][t] = *(const h8*)(agb[t] + (size_t)c*aggN + idx*32);
    }
  };

  // prologue: stage phase 0 B, pin, prefetch A(0) and A(1)
  stageX(&Bsm[0][0], 0);
  __builtin_amdgcn_sched_barrier(0);
  loadA(0, 0);          // X-phase: 8 vmem ops
  loadA(1, 1);          // agg: 2 vmem ops
  // stage(0)=2 ops are the only ops older than the 10 A ops -> vmcnt(10)
  asm volatile("s_waitcnt vmcnt(10)\n\ts_barrier" ::: "memory");

  #pragma unroll
  for(int ph = 0; ph < NPH; ph++){
    const int sub = ph % 9;                 // 0 = X phase, 1..8 = idx 0..7
    const int bank = ph & 1;
    _Float16* cur = &Bsm[ph & 1][0];
    _Float16* nxt = &Bsm[(ph & 1) ^ 1][0];

    // copy current-phase A fragments (frees bank for the (p+2) prefetch)
    h8 cA[4]; h8 cS[2]; h8 cH[2];
    cA[0] = pA[bank][0]; cA[1] = pA[bank][1];
    if(sub == 0){
      cA[2] = pA[bank][2]; cA[3] = pA[bank][3];
      cS[0] = pS[bank][0]; cS[1] = pS[bank][1];
      cH[0] = pH[bank][0]; cH[1] = pH[bank][1];
    }

    // 1. stage next phase's B tiles (buffer released by last phase's barrier)
    if(ph + 1 < NPH){
      const int c2   = (ph + 1) / 9;
      const int sub2 = (ph + 1) % 9;
      if(sub2 == 0) stageX(nxt, c2);
      else          stageP(nxt, c2, sub2 - 1);
    }
    __builtin_amdgcn_sched_barrier(0);   // pin: stage ops are oldest this phase

    // 2. prefetch A for phase p+2 into this bank
    loadA(ph + 2, bank);

    // 3. compute current phase from LDS
    __builtin_amdgcn_s_setprio(1);
    if(sub == 0){
      #pragma unroll
      for(int kb = 0; kb < 2; kb++)
        #pragma unroll
        for(int t = 0; t < 2; t++){
          h8 ax = cA[kb*2+t]*cS[kb] + cH[kb];
          #pragma unroll
          for(int nn = 0; nn < 4; nn++)
            acc[t][nn] = __builtin_amdgcn_mfma_f32_16x16x32_f16(
                ax, *(const h8*)(cur + (kb*4+nn)*512 + lane*8), acc[t][nn], 0,0,0);
        }
    } else {
      #pragma unroll
      for(int t = 0; t < 2; t++){
        h8 apl = cA[t];
        h8 aam = apl * am16[t];
        h8 aat = apl * at16[t];
        #pragma unroll
        for(int nn = 0; nn < 4; nn++){
          acc[t][nn] = __builtin_amdgcn_mfma_f32_16x16x32_f16(
              apl, *(const h8*)(cur + (0*4+nn)*512 + lane*8), acc[t][nn], 0,0,0);
          acc[t][nn] = __builtin_amdgcn_mfma_f32_16x16x32_f16(
              aam, *(const h8*)(cur + (4+nn)*512 + lane*8), acc[t][nn], 0,0,0);
          acc[t][nn] = __builtin_amdgcn_mfma_f32_16x16x32_f16(
              aat, *(const h8*)(cur + (8+nn)*512 + lane*8), acc[t][nn], 0,0,0);
        }
      }
    }
    __builtin_amdgcn_s_setprio(0);

    // 4. counted wait + barrier: prove stage(p+1) landed; leave A(p+2) in flight
    if(ph + 1 < NPH){
      const int ka = (ph + 2 < NPH) ? (((ph + 2) % 9 == 0) ? 8 : 2) : 0;
      if(ka == 8)      asm volatile("s_waitcnt vmcnt(8)\n\ts_barrier" ::: "memory");
      else if(ka == 2) asm volatile("s_waitcnt vmcnt(2)\n\ts_barrier" ::: "memory");
      else             asm volatile("s_waitcnt vmcnt(0)\n\ts_barrier" ::: "memory");
    }
  }

  __syncthreads();   // redS/redQ zero-init visible; full drain before epilogue

  // ---- epilogue: +bias, ReLU, store, stats via q-fold shuffles ----
  #pragma unroll
  for(int nn = 0; nn < 4; nn++){
    int n = c0 + nn*16 + mi;
    float bv = bias[n];
    float ps = 0.f, pq = 0.f;
    #pragma unroll
    for(int t = 0; t < 2; t++){
      #pragma unroll
      for(int r = 0; r < 4; r++){
        int m = m0 + t*16 + q*4 + r;
        if(m < NN){
          float v = fmaxf(bv + acc[t][nn][r], 0.f);
          out[(size_t)m*o + n] = (_Float16)v;
          ps += v; pq += v*v;
        }
      }
    }
    ps += __shfl_xor(ps, 16); pq += __shfl_xor(pq, 16);
    ps += __shfl_xor(ps, 32); pq += __shfl_xor(pq, 32);
    if(q == 0){
      atomicAdd(&redS[nn*16 + mi], ps);
      atomicAdd(&redQ[nn*16 + mi], pq);
    }
  }
  __syncthreads();
  if(tid < 64){
    atomicAdd(&colsum[c0 + tid], redS[tid]);
    atomicAdd(&colss[c0 + tid],  redQ[tid]);
  }
}

// ---------------- classifier (applies final BN affine on load) ----------------

__global__ __launch_bounds__(256) void k_cls(const _Float16* __restrict__ h,
    const float* __restrict__ cs, const float* __restrict__ csh,
    const float* __restrict__ Wc, const float* __restrict__ bc,
    float* __restrict__ out){
  __shared__ float w[640];
  __shared__ float bb[16];
  __shared__ float sca[64], shb[64];
  int tid = threadIdx.x;
  for(int i = tid; i < 640; i += 256) w[i] = Wc[i];
  if(tid < 10) bb[tid] = bc[tid];
  if(tid < 64){ sca[tid] = cs[tid]; shb[tid] = csh[tid]; }
  __syncthreads();
  int idx = blockIdx.x*256 + tid;
  int n = idx >> 4;
  int c = idx & 15;
  if(n < NN && c < 10){
    float acc = bb[c];
    const _Float16* hp = h + (size_t)n*64;
    #pragma unroll
    for(int k = 0; k < 64; k++)
      acc += ((float)hp[k]*sca[k] + shb[k]) * w[k*10 + c];
    out[(size_t)n*10 + c] = acc;
  }
}

// ---------------- launch ----------------

extern "C" void kernel_launch(void* const* d_in, const int* in_sizes, int n_in,
                              void* d_out, int out_size, void* d_ws, size_t ws_size,
                              hipStream_t stream){
  const float* x = (const float*)d_in[0];
  const int* edge = (const int*)d_in[1];
  const int* esrc = edge;
  const int* edst = edge + NE;
  const float* W[4]  = {(const float*)d_in[2],  (const float*)d_in[6],
                        (const float*)d_in[10], (const float*)d_in[14]};
  const float* bb[4] = {(const float*)d_in[3],  (const float*)d_in[7],
                        (const float*)d_in[11], (const float*)d_in[15]};
  const float* gm[4] = {(const float*)d_in[4],  (const float*)d_in[8],
                        (const float*)d_in[12], (const float*)d_in[16]};
  const float* bt[4] = {(const float*)d_in[5],  (const float*)d_in[9],
                        (const float*)d_in[13], (const float*)d_in[17]};
  const float* Wc = (const float*)d_in[18];
  const float* bc = (const float*)d_in[19];
  (void)in_sizes; (void)n_in; (void)out_size; (void)ws_size;

  // workspace carve (~158 MB; proven-safe envelope)
  char* p = (char*)d_ws;
  auto alloc = [&](size_t bytes)->char*{
    char* r = p; p += (bytes + 255) & ~(size_t)255; return r;
  };
  _Float16* act0 = (_Float16*)alloc((size_t)NN*256*2);   // 25.6 MB
  _Float16* act1 = (_Float16*)alloc((size_t)NN*256*2);   // 25.6 MB
  _Float16* aggs = (_Float16*)alloc((size_t)4*NN*256*2); // 102.4 MB: [chunk][N][256]
  int*   deg    = (int*)  alloc((size_t)NN*4);
  float* logdeg = (float*)alloc((size_t)NN*4);
  float* amp    = (float*)alloc((size_t)NN*4);
  float* att    = (float*)alloc((size_t)NN*4);
  int*   rowptr = (int*)  alloc((size_t)(NN+1)*4);
  int*   cursor = (int*)  alloc((size_t)NN*4);
  int*   colidx = (int*)  alloc((size_t)NE*4);
  int*   bsum   = (int*)  alloc((size_t)(NB+1)*4);
  float* colsumL= (float*)alloc(4*256*4);   // per-layer BN partials
  float* colssL = (float*)alloc(4*256*4);
  float* dsum   = (float*)alloc(256);
  // BN coefficient double-buffers (fp32 + fp16)
  float*    csA  = (float*)   alloc(256*4);
  float*    cshA = (float*)   alloc(256*4);
  float*    csB  = (float*)   alloc(256*4);
  float*    cshB = (float*)   alloc(256*4);
  _Float16* cs16A  = (_Float16*)alloc(256*2);
  _Float16* csh16A = (_Float16*)alloc(256*2);
  _Float16* cs16B  = (_Float16*)alloc(256*2);
  _Float16* csh16B = (_Float16*)alloc(256*2);

  const int din[4]  = {64, 128, 256, 128};
  const int dto[4]  = {128, 256, 128, 64};
  const size_t aggN = (size_t)NN*256;      // halves per chunk slab
  _Float16* WpL[4];
  PackArgs pa; int pj = 0, poff = 0;
  for(int l = 0; l < 4; l++){
    int nch = din[l]/64;
    WpL[l] = (_Float16*)alloc((size_t)nch*832*dto[l]*2);
    for(int c = 0; c < nch; c++){
      pa.job[pj] = { W[l], WpL[l] + (size_t)c*832*dto[l], din[l], dto[l], c*64, poff };
      poff += 832*dto[l]; pj++;
    }
  }
  pa.total = poff;

  hipMemsetAsync(deg, 0, (size_t)NN*4, stream);
  hipMemsetAsync(dsum, 0, 4, stream);
  hipMemsetAsync(colsumL, 0, 4*256*4, stream);
  hipMemsetAsync(colssL,  0, 4*256*4, stream);

  k_pack_all<<<(pa.total+255)/256, 256, 0, stream>>>(pa);
  k_deg     <<<(NE+255)/256, 256, 0, stream>>>(edst, deg);
  k_logdeg  <<<(NN+255)/256, 256, 0, stream>>>(deg, logdeg, dsum);
  k_scalers <<<(NN+255)/256, 256, 0, stream>>>(logdeg, dsum, amp, att);
  k_scan1   <<<NB, 1024, 0, stream>>>(deg, rowptr, bsum);
  k_scan2   <<<1, 64, 0, stream>>>(bsum);
  k_scan3   <<<(NN+256)/256, 256, 0, stream>>>(rowptr, cursor, bsum);
  k_fill    <<<(NE+255)/256, 256, 0, stream>>>(esrc, edst, cursor, colidx);
  k_cvtx    <<<(NN*64+255)/256, 256, 0, stream>>>(x, act0);
  k_coef_id <<<1, 256, 0, stream>>>(csA, cshA, cs16A, csh16A);

  _Float16* actIn = act0;  _Float16* actOut = act1;
  float *csI = csA, *cshI = cshA, *csO = csB, *cshO = cshB;
  _Float16 *cs16I = cs16A, *csh16I = csh16A, *cs16O = cs16B, *csh16O = csh16B;

  for(int l = 0; l < 4; l++){
    int d = din[l], o = dto[l];
    int npb = (32 / (d >> 3)) * 4;          // nodes per block in k_agg2t
    int nagg = (NN + npb - 1) / npb;
    dim3 g(o/64, (NN+127)/128);
    float* csum = colsumL + l*256;
    float* csq  = colssL + l*256;
    switch(d){
      case 64:
        k_agg2t<64><<<nagg, 256, 0, stream>>>(actIn, rowptr, colidx, csI, cshI, aggs, aggN);
        k_mfma_fused<1><<<g, 256, 0, stream>>>(actIn, aggs, amp, att, cs16I, csh16I,
                                               WpL[l], o, bb[l], actOut, csum, csq, aggN);
        break;
      case 128:
        k_agg2t<128><<<nagg, 256, 0, stream>>>(actIn, rowptr, colidx, csI, cshI, aggs, aggN);
        k_mfma_fused<2><<<g, 256, 0, stream>>>(actIn, aggs, amp, att, cs16I, csh16I,
                                               WpL[l], o, bb[l], actOut, csum, csq, aggN);
        break;
      default:
        k_agg2t<256><<<nagg, 256, 0, stream>>>(actIn, rowptr, colidx, csI, cshI, aggs, aggN);
        k_mfma_fused<4><<<g, 256, 0, stream>>>(actIn, aggs, amp, att, cs16I, csh16I,
                                               WpL[l], o, bb[l], actOut, csum, csq, aggN);
        break;
    }
    k_bn_coef<<<1, 256, 0, stream>>>(csum, csq, gm[l], bt[l], o,
                                     csO, cshO, cs16O, csh16O);
    // swap activation and coefficient buffers
    _Float16* ta = actIn; actIn = actOut; actOut = ta;
    float* tf;
    tf = csI;  csI = csO;  csO = tf;
    tf = cshI; cshI = cshO; cshO = tf;
    _Float16* th;
    th = cs16I;  cs16I = cs16O;  cs16O = th;
    th = csh16I; csh16I = csh16O; csh16O = th;
  }
  k_cls<<<(NN*16+255)/256, 256, 0, stream>>>(actIn, csI, cshI, Wc, bc, (float*)d_out);
}

// Round 9
// 709.460 us; speedup vs baseline: 1.0566x; 1.0566x over previous
//
#include <hip/hip_runtime.h>
#include <hip/hip_bf16.h>

#define NN 50000
#define NE 800000
#define EPSV 1e-5f
#define NB 49   // scan blocks: ceil(NN/1024)

typedef _Float16 h8 __attribute__((ext_vector_type(8)));
typedef _Float16 h2 __attribute__((ext_vector_type(2)));
typedef float    f4 __attribute__((ext_vector_type(4)));

#define AS1 __attribute__((address_space(1)))
#define AS3 __attribute__((address_space(3)))

__device__ __forceinline__ void gload_lds16(const _Float16* g, _Float16* l){
  __builtin_amdgcn_global_load_lds((const AS1 void*)g, (AS3 void*)l, 16, 0, 0);
}

// ---------------- graph preprocessing ----------------

__global__ void k_deg(const int* __restrict__ dst, int* __restrict__ deg){
  int e = blockIdx.x*blockDim.x + threadIdx.x;
  if(e < NE) atomicAdd(&deg[dst[e]], 1);
}

__global__ void k_logdeg(const int* __restrict__ deg, float* __restrict__ logdeg,
                         float* __restrict__ dsum){
  int i = blockIdx.x*blockDim.x + threadIdx.x;
  float v = 0.f;
  if(i < NN){ v = log1pf((float)deg[i]); logdeg[i] = v; }
  __shared__ float sh[256];
  sh[threadIdx.x] = v; __syncthreads();
  for(int off=128; off>0; off>>=1){
    if(threadIdx.x < off) sh[threadIdx.x] += sh[threadIdx.x+off];
    __syncthreads();
  }
  if(threadIdx.x == 0) atomicAdd(dsum, sh[0]);
}

__global__ void k_scalers(const float* __restrict__ logdeg, const float* __restrict__ dsum,
                          float* __restrict__ amp, float* __restrict__ att){
  int i = blockIdx.x*blockDim.x + threadIdx.x;
  if(i >= NN) return;
  float delta = dsum[0] / (float)NN;
  float ld = logdeg[i];
  amp[i] = ld / delta;
  att[i] = (ld > 0.f) ? (delta / fmaxf(ld, 1e-6f)) : 1.f;
}

// 3-phase parallel exclusive scan of deg -> rowptr (+cursor copy)
__global__ void k_scan1(const int* __restrict__ deg, int* __restrict__ rowptr,
                        int* __restrict__ bsum){
  __shared__ int buf[1024];
  int tid = threadIdx.x;
  int i = blockIdx.x*1024 + tid;
  int v = (i < NN) ? deg[i] : 0;
  buf[tid] = v; __syncthreads();
  for(int off=1; off<1024; off<<=1){
    int t = (tid >= off) ? buf[tid-off] : 0;
    __syncthreads();
    buf[tid] += t;
    __syncthreads();
  }
  if(i < NN) rowptr[i] = buf[tid] - v;
  if(tid == 1023) bsum[blockIdx.x] = buf[1023];
}

__global__ void k_scan2(int* __restrict__ bsum){
  if(threadIdx.x == 0){
    int s = 0;
    for(int b = 0; b < NB; b++){ int t = bsum[b]; bsum[b] = s; s += t; }
    bsum[NB] = s;
  }
}

__global__ void k_scan3(int* __restrict__ rowptr, int* __restrict__ cursor,
                        const int* __restrict__ bsum){
  int i = blockIdx.x*256 + threadIdx.x;
  if(i < NN){
    int v = rowptr[i] + bsum[i >> 10];
    rowptr[i] = v; cursor[i] = v;
  }
  if(i == NN) rowptr[NN] = bsum[NB];
}

__global__ void k_fill(const int* __restrict__ src, const int* __restrict__ dst,
                       int* __restrict__ cursor, int* __restrict__ colidx){
  int e = blockIdx.x*blockDim.x + threadIdx.x;
  if(e < NE){
    int pos = atomicAdd(&cursor[dst[e]], 1);
    colidx[pos] = src[e];
  }
}

__global__ void k_cvtx(const float* __restrict__ x, _Float16* __restrict__ act){
  int i = blockIdx.x*256 + threadIdx.x;
  if(i < NN*64) act[i] = (_Float16)x[i];
}

// identity BN coefficients for layer 1
__global__ void k_coef_id(float* __restrict__ cs, float* __restrict__ csh,
                          _Float16* __restrict__ cs16, _Float16* __restrict__ csh16){
  int c = threadIdx.x;
  cs[c] = 1.f; csh[c] = 0.f;
  cs16[c] = (_Float16)1.f; csh16[c] = (_Float16)0.f;
}

// BN coefficients from stats: v' = a*v + b with a=inv*gamma, b=beta-mean*a
__global__ void k_bn_coef(const float* __restrict__ colsum, const float* __restrict__ colss,
                          const float* __restrict__ gamma, const float* __restrict__ beta,
                          int dout, float* __restrict__ cs, float* __restrict__ csh,
                          _Float16* __restrict__ cs16, _Float16* __restrict__ csh16){
  int c = threadIdx.x;
  if(c >= dout) return;
  float mean = colsum[c] / (float)NN;
  float var  = colss[c] / (float)NN - mean*mean;
  float inv  = rsqrtf(fmaxf(var, 0.f) + EPSV);
  float a = inv * gamma[c];
  float b = beta[c] - mean * a;
  cs[c] = a; csh[c] = b;
  cs16[c] = (_Float16)a; csh16[c] = (_Float16)b;
}

// ---------------- aggregation: 2-team edge-split, mix-fma/packed VALU ----------

template<int D>
__global__ __launch_bounds__(256) void k_agg2t(
    const _Float16* __restrict__ act,
    const int* __restrict__ rowptr, const int* __restrict__ colidx,
    const float* __restrict__ cs, const float* __restrict__ csh,
    _Float16* __restrict__ aggs, size_t aggN)
{
  constexpr int CL  = D >> 3;       // col-lanes per team: 8/16/32
  constexpr int LPN = CL * 2;       // lanes per node (2 teams)
  constexpr int NPW = 64 / LPN;     // nodes per wave: 4/2/1
  int wv = threadIdx.x >> 6, lane = threadIdx.x & 63;
  int n = blockIdx.x*(NPW*4) + wv*NPW + (lane / LPN);
  int team = (lane / CL) & 1;
  int c = (lane % CL) * 8;          // 8 adjacent feature cols
  if(n >= NN) return;
  int beg = rowptr[n], end = rowptr[n+1];
  int deg = end - beg;
  int half1 = (deg + 1) >> 1;
  int tb = team ? (beg + half1) : beg;
  int te = team ? end : (beg + half1);
  const _Float16* hp = act + c;

  float s[8], q[8];
  h2 mnh[4], mxh[4];
  #pragma unroll
  for(int j = 0; j < 8; j++){ s[j]=0.f; q[j]=0.f; }
  #pragma unroll
  for(int p = 0; p < 4; p++){
    mnh[p] = h2{(_Float16)INFINITY, (_Float16)INFINITY};
    mxh[p] = h2{(_Float16)(-INFINITY), (_Float16)(-INFINITY)};
  }

#define ACC8(v) { \
  _Pragma("unroll") for(int j=0;j<8;j++){ \
    float a_ = (float)(v)[j]; \
    s[j] = fmaf(a_, 1.0f, s[j]); \
    q[j] = fmaf(a_, a_, q[j]); \
  } \
  _Pragma("unroll") for(int p=0;p<4;p++){ \
    h2 pr_ = h2{(v)[2*p], (v)[2*p+1]}; \
    mnh[p] = __builtin_elementwise_min(mnh[p], pr_); \
    mxh[p] = __builtin_elementwise_max(mxh[p], pr_); \
  } \
}

  int e = tb;
  for(; e+8 <= te; e+=8){
    int i0=colidx[e],   i1=colidx[e+1], i2=colidx[e+2], i3=colidx[e+3];
    int i4=colidx[e+4], i5=colidx[e+5], i6=colidx[e+6], i7=colidx[e+7];
    h8 v0 = *(const h8*)(hp + (size_t)i0*D);
    h8 v1 = *(const h8*)(hp + (size_t)i1*D);
    h8 v2 = *(const h8*)(hp + (size_t)i2*D);
    h8 v3 = *(const h8*)(hp + (size_t)i3*D);
    h8 v4 = *(const h8*)(hp + (size_t)i4*D);
    h8 v5 = *(const h8*)(hp + (size_t)i5*D);
    h8 v6 = *(const h8*)(hp + (size_t)i6*D);
    h8 v7 = *(const h8*)(hp + (size_t)i7*D);
    ACC8(v0) ACC8(v1) ACC8(v2) ACC8(v3) ACC8(v4) ACC8(v5) ACC8(v6) ACC8(v7)
  }
  for(; e+4 <= te; e+=4){
    int i0=colidx[e], i1=colidx[e+1], i2=colidx[e+2], i3=colidx[e+3];
    h8 v0 = *(const h8*)(hp + (size_t)i0*D);
    h8 v1 = *(const h8*)(hp + (size_t)i1*D);
    h8 v2 = *(const h8*)(hp + (size_t)i2*D);
    h8 v3 = *(const h8*)(hp + (size_t)i3*D);
    ACC8(v0) ACC8(v1) ACC8(v2) ACC8(v3)
  }
  for(; e < te; e++){
    h8 v = *(const h8*)(hp + (size_t)colidx[e]*D);
    ACC8(v)
  }
#undef ACC8

  // combine teams: partner lane differs only in the team bit (same node)
  #pragma unroll
  for(int j = 0; j < 8; j++){
    s[j] += __shfl_xor(s[j], CL);
    q[j] += __shfl_xor(q[j], CL);
  }
  #pragma unroll
  for(int p = 0; p < 4; p++){
    int bn = __shfl_xor(__builtin_bit_cast(int, mnh[p]), CL);
    int bx = __shfl_xor(__builtin_bit_cast(int, mxh[p]), CL);
    mnh[p] = __builtin_elementwise_min(mnh[p], __builtin_bit_cast(h2, bn));
    mxh[p] = __builtin_elementwise_max(mxh[p], __builtin_bit_cast(h2, bx));
  }
  if(team) return;                  // team 0 writes the result

  float cnt = (deg > 0) ? (float)deg : 1.f;
  h8 vm, vn, vx, vs;
  #pragma unroll
  for(int j = 0; j < 8; j++){
    float a = cs[c+j], b = csh[c+j];
    float mnv = (float)mnh[j>>1][j&1];
    float mxv = (float)mxh[j>>1][j&1];
    float mean_r = s[j]/cnt;
    float var_r  = fmaxf(q[j]/cnt - mean_r*mean_r, 0.f);
    float meanp = a*mean_r + b;
    float mnp = (a >= 0.f) ? a*mnv+b : a*mxv+b;
    float mxp = (a >= 0.f) ? a*mxv+b : a*mnv+b;
    float sdp = sqrtf(a*a*var_r + EPSV);
    if(deg <= 0){ meanp = 0.f; mnp = 0.f; mxp = 0.f; sdp = sqrtf(EPSV); }
    vm[j] = (_Float16)meanp; vn[j] = (_Float16)mnp;
    vx[j] = (_Float16)mxp;   vs[j] = (_Float16)sdp;
  }

  _Float16* dst = aggs + (size_t)(c>>6)*aggN + (size_t)n*256 + (c & 63);
  *(h8*)(dst)       = vm;
  *(h8*)(dst + 64)  = vn;
  *(h8*)(dst + 128) = vx;
  *(h8*)(dst + 192) = vs;
}

// ---------------- fused W pre-pack (all layers/chunks, one kernel) ----------------

struct PackJob { const float* W; _Float16* dst; int d, o, j0, start; };
struct PackArgs { PackJob job[9]; int total; };

__global__ void k_pack_all(PackArgs a){
  int idx = blockIdx.x*256 + threadIdx.x;
  if(idx >= a.total) return;
  int ji = 0;
  while(ji < 8 && idx >= a.job[ji+1].start) ji++;
  PackJob J = a.job[ji];
  int rel = idx - J.start;
  int j    = rel & 7;
  int lane = (rel >> 3) & 63;
  int rem  = rel >> 9;
  int ntiles = J.o >> 4;
  int kb = rem / ntiles;
  int nt = rem - kb*ntiles;
  int k = kb*32 + (lane>>4)*8 + j;
  int n = nt*16 + (lane&15);
  int srcrow;
  if(k < 64)       srcrow = J.j0 + k;
  else if(k < 320){ int t=k-64;  srcrow = (1+(t>>6))*J.d + J.j0 + (t&63); }
  else if(k < 576){ int t=k-320; srcrow = (5+(t>>6))*J.d + J.j0 + (t&63); }
  else            { int t=k-576; srcrow = (9+(t>>6))*J.d + J.j0 + (t&63); }
  J.dst[rel] = (_Float16)J.W[(size_t)srcrow*J.o + n];
}

// ---------------- fused MFMA layer GEMM: TRIPLE-buffered B, true counted vmcnt --
// r2's vmcnt(2) at the barrier force-drained A(p+1) (in-order queue) -> ~400
// cyc/phase all-wave stall when aggs misses L3 (fused<4>). Fix: 3 LDS buffers,
// stage phase p+2 (not p+1) in phase p. End-of-phase wait vmcnt(K), K =
// a(p+1)+s(p+2)+a(p+2): proves stage(p+1) (issued a full phase ago) while
// leaving A(p+1) in flight across the barrier -- its landing is enforced by
// the compiler's per-wave use-wait at the next phase's register copy, where
// other waves keep running. A gets ~2 phases of latency cover.

template<int NCH>
__global__ __launch_bounds__(256) void k_mfma_fused(
    const _Float16* __restrict__ actIn,
    const _Float16* __restrict__ aggs,          // [NCH][NN][256]
    const float* __restrict__ amp, const float* __restrict__ att,
    const _Float16* __restrict__ cs16, const _Float16* __restrict__ csh16,
    const _Float16* __restrict__ Wp, int o,     // [NCH][832*o]
    const float* __restrict__ bias,
    _Float16* __restrict__ out,                 // [NN][o], relu'd pre-BN
    float* __restrict__ colsum, float* __restrict__ colss,
    size_t aggN)
{
  constexpr int D = NCH * 64;
  constexpr int NPH = NCH * 9;
  __shared__ _Float16 Bsm[3][12*512];           // 3 x 12 KB triple buffer
  __shared__ float redS[64], redQ[64];
  int tid  = threadIdx.x;
  int wv   = tid >> 6;
  int lane = tid & 63;
  int mi   = lane & 15;
  int q    = lane >> 4;

  // bijective XCD swizzle (m204): same-y blocks land on same XCD's L2
  int T  = gridDim.x * gridDim.y;
  int n_ = blockIdx.y * gridDim.x + blockIdx.x;
  int qq = T >> 3, rr = T & 7, xc = n_ & 7, nl = n_ >> 3;
  int m_ = (xc < rr ? xc*(qq+1) : rr*(qq+1) + (xc-rr)*qq) + nl;
  int bx = m_ % gridDim.x;
  int by = m_ / gridDim.x;

  int m0   = by * 128 + wv * 32;
  int c0   = bx * 64;
  int ntiles = o >> 4;
  int nt0  = bx * 4;

  if(tid < 64){ redS[tid] = 0.f; redQ[tid] = 0.f; }

  int mrow[2];
  mrow[0] = min(m0 + mi,      NN-1);
  mrow[1] = min(m0 + 16 + mi, NN-1);
  _Float16 am16[2] = { (_Float16)amp[mrow[0]], (_Float16)amp[mrow[1]] };
  _Float16 at16[2] = { (_Float16)att[mrow[0]], (_Float16)att[mrow[1]] };
  const _Float16* hAb[2];
  const _Float16* agb[2];
  hAb[0] = actIn + (size_t)mrow[0]*D + q*8;
  hAb[1] = actIn + (size_t)mrow[1]*D + q*8;
  agb[0] = aggs + (size_t)mrow[0]*256 + q*8;
  agb[1] = aggs + (size_t)mrow[1]*256 + q*8;

  f4 acc[2][4] = {};

  // B-tile staging: tile ti lives at buf[ti*512 + lane*8]
  auto stageX = [&](_Float16* buf, int c){
    const _Float16* Wpc = Wp + (size_t)c*832*o;
    #pragma unroll
    for(int s = 0; s < 2; s++){
      int ti = wv*2 + s;
      int kb = ti >> 2, nn = ti & 3;
      gload_lds16(Wpc + (((size_t)kb*ntiles + nt0 + nn)*64 + lane)*8,
                  buf + ti*512);
    }
  };
  auto stageP = [&](_Float16* buf, int c, int idx){
    const _Float16* Wpc = Wp + (size_t)c*832*o;
    #pragma unroll
    for(int s = 0; s < 3; s++){
      int ti = wv*3 + s;
      int kj = ti >> 2, nn = ti & 3;
      int kb = (kj == 0 ? 2 : (kj == 1 ? 10 : 18)) + idx;
      gload_lds16(Wpc + (((size_t)kb*ntiles + nt0 + nn)*64 + lane)*8,
                  buf + ti*512);
    }
  };
  auto stagePh = [&](int p2){
    int c2 = p2 / 9, s2 = p2 % 9;
    _Float16* buf = &Bsm[p2 % 3][0];
    if(s2 == 0) stageX(buf, c2);
    else        stageP(buf, c2, s2 - 1);
  };

  // A-prefetch register banks (2-phase lead, statically indexed after unroll)
  h8 pA[2][4]; h8 pS[2][2]; h8 pH[2][2];
  auto loadA = [&](int ph2, int bank){
    if(ph2 >= NPH) return;
    int c = ph2 / 9, sub = ph2 % 9;
    if(sub == 0){
      #pragma unroll
      for(int kb = 0; kb < 2; kb++){
        pS[bank][kb] = *(const h8*)(cs16  + c*64 + kb*32 + q*8);
        pH[bank][kb] = *(const h8*)(csh16 + c*64 + kb*32 + q*8);
        #pragma unroll
        for(int t = 0; t < 2; t++)
          pA[bank][kb*2+t] = *(const h8*)(hAb[t] + c*64 + kb*32);
      }
    } else {
      int idx = sub - 1;
      #pragma unroll
      for(int t = 0; t < 2; t++)
        pA[bank][t] = *(const h8*)(agb[t] + (size_t)c*aggN + idx*32);
    }
  };

  // prologue: stage phases 0 and 1, pin, prefetch A(0) and A(1).
  // VMEM order: stage0(2), stage1(3), A0(8), A1(2) -> wait stage0 = vmcnt(13)
  stagePh(0);
  __builtin_amdgcn_sched_barrier(0);
  stagePh(1);
  __builtin_amdgcn_sched_barrier(0);
  loadA(0, 0);
  loadA(1, 1);
  __builtin_amdgcn_sched_barrier(0);
  asm volatile("s_waitcnt vmcnt(13)\n\ts_barrier" ::: "memory");

  #pragma unroll
  for(int ph = 0; ph < NPH; ph++){
    const int sub = ph % 9;                 // 0 = X phase, 1..8 = idx 0..7
    const int bank = ph & 1;
    _Float16* cur = &Bsm[ph % 3][0];

    // copy current-phase A fragments (compiler's use-wait lands A(ph) here;
    // per-wave, not a barrier -- other waves keep running)
    h8 cA[4]; h8 cS[2]; h8 cH[2];
    cA[0] = pA[bank][0]; cA[1] = pA[bank][1];
    if(sub == 0){
      cA[2] = pA[bank][2]; cA[3] = pA[bank][3];
      cS[0] = pS[bank][0]; cS[1] = pS[bank][1];
      cH[0] = pH[bank][0]; cH[1] = pH[bank][1];
    }

    // 1. stage phase p+2's B tiles (buffer (p+2)%3 was read in phase p-1;
    //    the end-of-(p-1) barrier released it)
    if(ph + 2 < NPH) stagePh(ph + 2);
    __builtin_amdgcn_sched_barrier(0);   // pin: stage ops precede A ops

    // 2. prefetch A for phase p+2 into this bank (2-phase lead)
    loadA(ph + 2, bank);

    // 3. compute current phase from LDS
    __builtin_amdgcn_s_setprio(1);
    if(sub == 0){
      #pragma unroll
      for(int kb = 0; kb < 2; kb++)
        #pragma unroll
        for(int t = 0; t < 2; t++){
          h8 ax = cA[kb*2+t]*cS[kb] + cH[kb];
          #pragma unroll
          for(int nn = 0; nn < 4; nn++)
            acc[t][nn] = __builtin_amdgcn_mfma_f32_16x16x32_f16(
                ax, *(const h8*)(cur + (kb*4+nn)*512 + lane*8), acc[t][nn], 0,0,0);
        }
    } else {
      #pragma unroll
      for(int t = 0; t < 2; t++){
        h8 apl = cA[t];
        h8 aam = apl * am16[t];
        h8 aat = apl * at16[t];
        #pragma unroll
        for(int nn = 0; nn < 4; nn++){
          acc[t][nn] = __builtin_amdgcn_mfma_f32_16x16x32_f16(
              apl, *(const h8*)(cur + (0*4+nn)*512 + lane*8), acc[t][nn], 0,0,0);
          acc[t][nn] = __builtin_amdgcn_mfma_f32_16x16x32_f16(
              aam, *(const h8*)(cur + (4+nn)*512 + lane*8), acc[t][nn], 0,0,0);
          acc[t][nn] = __builtin_amdgcn_mfma_f32_16x16x32_f16(
              aat, *(const h8*)(cur + (8+nn)*512 + lane*8), acc[t][nn], 0,0,0);
        }
      }
    }
    __builtin_amdgcn_s_setprio(0);

    // 4. counted barrier: K = a(p+1) + s(p+2) + a(p+2) leaves A(p+1),
    //    stage(p+2), A(p+2) in flight; drains through stage(p+1).
    if(ph + 1 < NPH){
      const bool x1   = ((ph + 1) % 9) == 0;
      const bool has2 = (ph + 2) < NPH;
      const bool x2   = has2 && (((ph + 2) % 9) == 0);
      const int K = (x1 ? 8 : 2) + (has2 ? ((x2 ? 2 : 3) + (x2 ? 8 : 2)) : 0);
      if(K == 13)      asm volatile("s_waitcnt vmcnt(13)\n\ts_barrier" ::: "memory");
      else if(K == 12) asm volatile("s_waitcnt vmcnt(12)\n\ts_barrier" ::: "memory");
      else if(K == 7)  asm volatile("s_waitcnt vmcnt(7)\n\ts_barrier" ::: "memory");
      else             asm volatile("s_waitcnt vmcnt(2)\n\ts_barrier" ::: "memory");
    }
  }

  __syncthreads();   // redS/redQ zero-init visible; full drain before epilogue

  // ---- epilogue: +bias, ReLU, store, stats via q-fold shuffles ----
  #pragma unroll
  for(int nn = 0; nn < 4; nn++){
    int n = c0 + nn*16 + mi;
    float bv = bias[n];
    float ps = 0.f, pq = 0.f;
    #pragma unroll
    for(int t = 0; t < 2; t++){
      #pragma unroll
      for(int r = 0; r < 4; r++){
        int m = m0 + t*16 + q*4 + r;
        if(m < NN){
          float v = fmaxf(bv + acc[t][nn][r], 0.f);
          out[(size_t)m*o + n] = (_Float16)v;
          ps += v; pq += v*v;
        }
      }
    }
    ps += __shfl_xor(ps, 16); pq += __shfl_xor(pq, 16);
    ps += __shfl_xor(ps, 32); pq += __shfl_xor(pq, 32);
    if(q == 0){
      atomicAdd(&redS[nn*16 + mi], ps);
      atomicAdd(&redQ[nn*16 + mi], pq);
    }
  }
  __syncthreads();
  if(tid < 64){
    atomicAdd(&colsum[c0 + tid], redS[tid]);
    atomicAdd(&colss[c0 + tid],  redQ[tid]);
  }
}

// ---------------- classifier (applies final BN affine on load) ----------------

__global__ __launch_bounds__(256) void k_cls(const _Float16* __restrict__ h,
    const float* __restrict__ cs, const float* __restrict__ csh,
    const float* __restrict__ Wc, const float* __restrict__ bc,
    float* __restrict__ out){
  __shared__ float w[640];
  __shared__ float bb[16];
  __shared__ float sca[64], shb[64];
  int tid = threadIdx.x;
  for(int i = tid; i < 640; i += 256) w[i] = Wc[i];
  if(tid < 10) bb[tid] = bc[tid];
  if(tid < 64){ sca[tid] = cs[tid]; shb[tid] = csh[tid]; }
  __syncthreads();
  int idx = blockIdx.x*256 + tid;
  int n = idx >> 4;
  int c = idx & 15;
  if(n < NN && c < 10){
    float acc = bb[c];
    const _Float16* hp = h + (size_t)n*64;
    #pragma unroll
    for(int k = 0; k < 64; k++)
      acc += ((float)hp[k]*sca[k] + shb[k]) * w[k*10 + c];
    out[(size_t)n*10 + c] = acc;
  }
}

// ---------------- launch ----------------

extern "C" void kernel_launch(void* const* d_in, const int* in_sizes, int n_in,
                              void* d_out, int out_size, void* d_ws, size_t ws_size,
                              hipStream_t stream){
  const float* x = (const float*)d_in[0];
  const int* edge = (const int*)d_in[1];
  const int* esrc = edge;
  const int* edst = edge + NE;
  const float* W[4]  = {(const float*)d_in[2],  (const float*)d_in[6],
                        (const float*)d_in[10], (const float*)d_in[14]};
  const float* bb[4] = {(const float*)d_in[3],  (const float*)d_in[7],
                        (const float*)d_in[11], (const float*)d_in[15]};
  const float* gm[4] = {(const float*)d_in[4],  (const float*)d_in[8],
                        (const float*)d_in[12], (const float*)d_in[16]};
  const float* bt[4] = {(const float*)d_in[5],  (const float*)d_in[9],
                        (const float*)d_in[13], (const float*)d_in[17]};
  const float* Wc = (const float*)d_in[18];
  const float* bc = (const float*)d_in[19];
  (void)in_sizes; (void)n_in; (void)out_size; (void)ws_size;

  // workspace carve (~158 MB; proven-safe envelope)
  char* p = (char*)d_ws;
  auto alloc = [&](size_t bytes)->char*{
    char* r = p; p += (bytes + 255) & ~(size_t)255; return r;
  };
  _Float16* act0 = (_Float16*)alloc((size_t)NN*256*2);   // 25.6 MB
  _Float16* act1 = (_Float16*)alloc((size_t)NN*256*2);   // 25.6 MB
  _Float16* aggs = (_Float16*)alloc((size_t)4*NN*256*2); // 102.4 MB: [chunk][N][256]
  int*   deg    = (int*)  alloc((size_t)NN*4);
  float* logdeg = (float*)alloc((size_t)NN*4);
  float* amp    = (float*)alloc((size_t)NN*4);
  float* att    = (float*)alloc((size_t)NN*4);
  int*   rowptr = (int*)  alloc((size_t)(NN+1)*4);
  int*   cursor = (int*)  alloc((size_t)NN*4);
  int*   colidx = (int*)  alloc((size_t)NE*4);
  int*   bsum   = (int*)  alloc((size_t)(NB+1)*4);
  float* colsumL= (float*)alloc(4*256*4);   // per-layer BN partials
  float* colssL = (float*)alloc(4*256*4);
  float* dsum   = (float*)alloc(256);
  // BN coefficient double-buffers (fp32 + fp16)
  float*    csA  = (float*)   alloc(256*4);
  float*    cshA = (float*)   alloc(256*4);
  float*    csB  = (float*)   alloc(256*4);
  float*    cshB = (float*)   alloc(256*4);
  _Float16* cs16A  = (_Float16*)alloc(256*2);
  _Float16* csh16A = (_Float16*)alloc(256*2);
  _Float16* cs16B  = (_Float16*)alloc(256*2);
  _Float16* csh16B = (_Float16*)alloc(256*2);

  const int din[4]  = {64, 128, 256, 128};
  const int dto[4]  = {128, 256, 128, 64};
  const size_t aggN = (size_t)NN*256;      // halves per chunk slab
  _Float16* WpL[4];
  PackArgs pa; int pj = 0, poff = 0;
  for(int l = 0; l < 4; l++){
    int nch = din[l]/64;
    WpL[l] = (_Float16*)alloc((size_t)nch*832*dto[l]*2);
    for(int c = 0; c < nch; c++){
      pa.job[pj] = { W[l], WpL[l] + (size_t)c*832*dto[l], din[l], dto[l], c*64, poff };
      poff += 832*dto[l]; pj++;
    }
  }
  pa.total = poff;

  hipMemsetAsync(deg, 0, (size_t)NN*4, stream);
  hipMemsetAsync(dsum, 0, 4, stream);
  hipMemsetAsync(colsumL, 0, 4*256*4, stream);
  hipMemsetAsync(colssL,  0, 4*256*4, stream);

  k_pack_all<<<(pa.total+255)/256, 256, 0, stream>>>(pa);
  k_deg     <<<(NE+255)/256, 256, 0, stream>>>(edst, deg);
  k_logdeg  <<<(NN+255)/256, 256, 0, stream>>>(deg, logdeg, dsum);
  k_scalers <<<(NN+255)/256, 256, 0, stream>>>(logdeg, dsum, amp, att);
  k_scan1   <<<NB, 1024, 0, stream>>>(deg, rowptr, bsum);
  k_scan2   <<<1, 64, 0, stream>>>(bsum);
  k_scan3   <<<(NN+256)/256, 256, 0, stream>>>(rowptr, cursor, bsum);
  k_fill    <<<(NE+255)/256, 256, 0, stream>>>(esrc, edst, cursor, colidx);
  k_cvtx    <<<(NN*64+255)/256, 256, 0, stream>>>(x, act0);
  k_coef_id <<<1, 256, 0, stream>>>(csA, cshA, cs16A, csh16A);

  _Float16* actIn = act0;  _Float16* actOut = act1;
  float *csI = csA, *cshI = cshA, *csO = csB, *cshO = cshB;
  _Float16 *cs16I = cs16A, *csh16I = csh16A, *cs16O = cs16B, *csh16O = csh16B;

  for(int l = 0; l < 4; l++){
    int d = din[l], o = dto[l];
    int npb = (32 / (d >> 3)) * 4;          // nodes per block in k_agg2t
    int nagg = (NN + npb - 1) / npb;
    dim3 g(o/64, (NN+127)/128);
    float* csum = colsumL + l*256;
    float* csq  = colssL + l*256;
    switch(d){
      case 64:
        k_agg2t<64><<<nagg, 256, 0, stream>>>(actIn, rowptr, colidx, csI, cshI, aggs, aggN);
        k_mfma_fused<1><<<g, 256, 0, stream>>>(actIn, aggs, amp, att, cs16I, csh16I,
                                               WpL[l], o, bb[l], actOut, csum, csq, aggN);
        break;
      case 128:
        k_agg2t<128><<<nagg, 256, 0, stream>>>(actIn, rowptr, colidx, csI, cshI, aggs, aggN);
        k_mfma_fused<2><<<g, 256, 0, stream>>>(actIn, aggs, amp, att, cs16I, csh16I,
                                               WpL[l], o, bb[l], actOut, csum, csq, aggN);
        break;
      default:
        k_agg2t<256><<<nagg, 256, 0, stream>>>(actIn, rowptr, colidx, csI, cshI, aggs, aggN);
        k_mfma_fused<4><<<g, 256, 0, stream>>>(actIn, aggs, amp, att, cs16I, csh16I,
                                               WpL[l], o, bb[l], actOut, csum, csq, aggN);
        break;
    }
    k_bn_coef<<<1, 256, 0, stream>>>(csum, csq, gm[l], bt[l], o,
                                     csO, cshO, cs16O, csh16O);
    // swap activation and coefficient buffers
    _Float16* ta = actIn; actIn = actOut; actOut = ta;
    float* tf;
    tf = csI;  csI = csO;  csO = tf;
    tf = cshI; cshI = cshO; cshO = tf;
    _Float16* th;
    th = cs16I;  cs16I = cs16O;  cs16O = th;
    th = csh16I; csh16I = csh16O; csh16O = th;
  }
  k_cls<<<(NN*16+255)/256, 256, 0, stream>>>(actIn, csI, cshI, Wc, bc, (float*)d_out);
}

// Round 10
// 651.789 us; speedup vs baseline: 1.1501x; 1.0885x over previous
//
#include <hip/hip_runtime.h>
#include <hip/hip_bf16.h>

#define NN 50000
#define NE 800000
#define EPSV 1e-5f
#define NB 49   // scan blocks: ceil(NN/1024)

typedef _Float16 h8 __attribute__((ext_vector_type(8)));
typedef float    f4 __attribute__((ext_vector_type(4)));

#define AS1 __attribute__((address_space(1)))
#define AS3 __attribute__((address_space(3)))

__device__ __forceinline__ void gload_lds16(const _Float16* g, _Float16* l){
  __builtin_amdgcn_global_load_lds((const AS1 void*)g, (AS3 void*)l, 16, 0, 0);
}

// ---------------- graph preprocessing ----------------

__global__ void k_deg(const int* __restrict__ dst, int* __restrict__ deg){
  int e = blockIdx.x*blockDim.x + threadIdx.x;
  if(e < NE) atomicAdd(&deg[dst[e]], 1);
}

__global__ void k_logdeg(const int* __restrict__ deg, float* __restrict__ logdeg,
                         float* __restrict__ dsum){
  int i = blockIdx.x*blockDim.x + threadIdx.x;
  float v = 0.f;
  if(i < NN){ v = log1pf((float)deg[i]); logdeg[i] = v; }
  __shared__ float sh[256];
  sh[threadIdx.x] = v; __syncthreads();
  for(int off=128; off>0; off>>=1){
    if(threadIdx.x < off) sh[threadIdx.x] += sh[threadIdx.x+off];
    __syncthreads();
  }
  if(threadIdx.x == 0) atomicAdd(dsum, sh[0]);
}

__global__ void k_scalers(const float* __restrict__ logdeg, const float* __restrict__ dsum,
                          float* __restrict__ amp, float* __restrict__ att){
  int i = blockIdx.x*blockDim.x + threadIdx.x;
  if(i >= NN) return;
  float delta = dsum[0] / (float)NN;
  float ld = logdeg[i];
  amp[i] = ld / delta;
  att[i] = (ld > 0.f) ? (delta / fmaxf(ld, 1e-6f)) : 1.f;
}

// 3-phase parallel exclusive scan of deg -> rowptr (+cursor copy)
__global__ void k_scan1(const int* __restrict__ deg, int* __restrict__ rowptr,
                        int* __restrict__ bsum){
  __shared__ int buf[1024];
  int tid = threadIdx.x;
  int i = blockIdx.x*1024 + tid;
  int v = (i < NN) ? deg[i] : 0;
  buf[tid] = v; __syncthreads();
  for(int off=1; off<1024; off<<=1){
    int t = (tid >= off) ? buf[tid-off] : 0;
    __syncthreads();
    buf[tid] += t;
    __syncthreads();
  }
  if(i < NN) rowptr[i] = buf[tid] - v;
  if(tid == 1023) bsum[blockIdx.x] = buf[1023];
}

__global__ void k_scan2(int* __restrict__ bsum){
  if(threadIdx.x == 0){
    int s = 0;
    for(int b = 0; b < NB; b++){ int t = bsum[b]; bsum[b] = s; s += t; }
    bsum[NB] = s;
  }
}

__global__ void k_scan3(int* __restrict__ rowptr, int* __restrict__ cursor,
                        const int* __restrict__ bsum){
  int i = blockIdx.x*256 + threadIdx.x;
  if(i < NN){
    int v = rowptr[i] + bsum[i >> 10];
    rowptr[i] = v; cursor[i] = v;
  }
  if(i == NN) rowptr[NN] = bsum[NB];
}

__global__ void k_fill(const int* __restrict__ src, const int* __restrict__ dst,
                       int* __restrict__ cursor, int* __restrict__ colidx){
  int e = blockIdx.x*blockDim.x + threadIdx.x;
  if(e < NE){
    int pos = atomicAdd(&cursor[dst[e]], 1);
    colidx[pos] = src[e];
  }
}

__global__ void k_cvtx(const float* __restrict__ x, _Float16* __restrict__ act){
  int i = blockIdx.x*256 + threadIdx.x;
  if(i < NN*64) act[i] = (_Float16)x[i];
}

// identity BN coefficients for layer 1
__global__ void k_coef_id(float* __restrict__ cs, float* __restrict__ csh,
                          _Float16* __restrict__ cs16, _Float16* __restrict__ csh16){
  int c = threadIdx.x;
  cs[c] = 1.f; csh[c] = 0.f;
  cs16[c] = (_Float16)1.f; csh16[c] = (_Float16)0.f;
}

// BN coefficients from stats: v' = a*v + b with a=inv*gamma, b=beta-mean*a
__global__ void k_bn_coef(const float* __restrict__ colsum, const float* __restrict__ colss,
                          const float* __restrict__ gamma, const float* __restrict__ beta,
                          int dout, float* __restrict__ cs, float* __restrict__ csh,
                          _Float16* __restrict__ cs16, _Float16* __restrict__ csh16){
  int c = threadIdx.x;
  if(c >= dout) return;
  float mean = colsum[c] / (float)NN;
  float var  = colss[c] / (float)NN - mean*mean;
  float inv  = rsqrtf(fmaxf(var, 0.f) + EPSV);
  float a = inv * gamma[c];
  float b = beta[c] - mean * a;
  cs[c] = a; csh[c] = b;
  cs16[c] = (_Float16)a; csh16[c] = (_Float16)b;
}

// ---------------- aggregation (templated on D): 8 cols/lane, 16 B loads ----------
// (r2-proven variant: full edge list per node, 8-deep load pipelining.
// r6's 2-team split regressed ~44 us total: half-lists defeat the 8-unroll.)

template<int D>
__global__ __launch_bounds__(256) void k_agg8(
    const _Float16* __restrict__ act,
    const int* __restrict__ rowptr, const int* __restrict__ colidx,
    const float* __restrict__ cs, const float* __restrict__ csh,
    _Float16* __restrict__ aggs, size_t aggN)
{
  constexpr int LPN = D >> 3;       // lanes per node: 8/16/32
  constexpr int NPW = 64 / LPN;     // nodes per wave: 8/4/2
  int wv = threadIdx.x >> 6, lane = threadIdx.x & 63;
  int n = blockIdx.x*(NPW*4) + wv*NPW + (lane / LPN);
  int c = (lane % LPN) * 8;         // 8 adjacent feature cols
  if(n >= NN) return;
  int beg = rowptr[n], end = rowptr[n+1];
  const _Float16* hp = act + c;

  float s[8], q[8], mn[8], mx[8];
  #pragma unroll
  for(int j = 0; j < 8; j++){ s[j]=0.f; q[j]=0.f; mn[j]=INFINITY; mx[j]=-INFINITY; }

#define ACC8(v) { _Pragma("unroll") for(int j=0;j<8;j++){ float a=(float)(v)[j]; \
    s[j]+=a; q[j]+=a*a; mn[j]=fminf(mn[j],a); mx[j]=fmaxf(mx[j],a); } }

  int e = beg;
  for(; e+8 <= end; e+=8){
    int i0=colidx[e],   i1=colidx[e+1], i2=colidx[e+2], i3=colidx[e+3];
    int i4=colidx[e+4], i5=colidx[e+5], i6=colidx[e+6], i7=colidx[e+7];
    h8 v0 = *(const h8*)(hp + (size_t)i0*D);
    h8 v1 = *(const h8*)(hp + (size_t)i1*D);
    h8 v2 = *(const h8*)(hp + (size_t)i2*D);
    h8 v3 = *(const h8*)(hp + (size_t)i3*D);
    h8 v4 = *(const h8*)(hp + (size_t)i4*D);
    h8 v5 = *(const h8*)(hp + (size_t)i5*D);
    h8 v6 = *(const h8*)(hp + (size_t)i6*D);
    h8 v7 = *(const h8*)(hp + (size_t)i7*D);
    ACC8(v0) ACC8(v1) ACC8(v2) ACC8(v3) ACC8(v4) ACC8(v5) ACC8(v6) ACC8(v7)
  }
  for(; e+4 <= end; e+=4){
    int i0=colidx[e], i1=colidx[e+1], i2=colidx[e+2], i3=colidx[e+3];
    h8 v0 = *(const h8*)(hp + (size_t)i0*D);
    h8 v1 = *(const h8*)(hp + (size_t)i1*D);
    h8 v2 = *(const h8*)(hp + (size_t)i2*D);
    h8 v3 = *(const h8*)(hp + (size_t)i3*D);
    ACC8(v0) ACC8(v1) ACC8(v2) ACC8(v3)
  }
  for(; e < end; e++){
    h8 v = *(const h8*)(hp + (size_t)colidx[e]*D);
    ACC8(v)
  }
#undef ACC8

  float cnt = (end>beg) ? (float)(end-beg) : 1.f;
  h8 vm, vn, vx, vs;
  #pragma unroll
  for(int j = 0; j < 8; j++){
    float a = cs[c+j], b = csh[c+j];
    float mean_r = s[j]/cnt;
    float var_r  = fmaxf(q[j]/cnt - mean_r*mean_r, 0.f);
    float meanp = a*mean_r + b;
    float mnp = (a >= 0.f) ? a*mn[j]+b : a*mx[j]+b;
    float mxp = (a >= 0.f) ? a*mx[j]+b : a*mn[j]+b;
    float sdp = sqrtf(a*a*var_r + EPSV);
    if(end <= beg){ meanp = 0.f; mnp = 0.f; mxp = 0.f; sdp = sqrtf(EPSV); }
    vm[j] = (_Float16)meanp; vn[j] = (_Float16)mnp;
    vx[j] = (_Float16)mxp;   vs[j] = (_Float16)sdp;
  }

  _Float16* dst = aggs + (size_t)(c>>6)*aggN + (size_t)n*256 + (c & 63);
  *(h8*)(dst)       = vm;
  *(h8*)(dst + 64)  = vn;
  *(h8*)(dst + 128) = vx;
  *(h8*)(dst + 192) = vs;
}

// ---------------- fused W pre-pack (all layers/chunks, one kernel) ----------------

struct PackJob { const float* W; _Float16* dst; int d, o, j0, start; };
struct PackArgs { PackJob job[9]; int total; };

__global__ void k_pack_all(PackArgs a){
  int idx = blockIdx.x*256 + threadIdx.x;
  if(idx >= a.total) return;
  int ji = 0;
  while(ji < 8 && idx >= a.job[ji+1].start) ji++;
  PackJob J = a.job[ji];
  int rel = idx - J.start;
  int j    = rel & 7;
  int lane = (rel >> 3) & 63;
  int rem  = rel >> 9;
  int ntiles = J.o >> 4;
  int kb = rem / ntiles;
  int nt = rem - kb*ntiles;
  int k = kb*32 + (lane>>4)*8 + j;
  int n = nt*16 + (lane&15);
  int srcrow;
  if(k < 64)       srcrow = J.j0 + k;
  else if(k < 320){ int t=k-64;  srcrow = (1+(t>>6))*J.d + J.j0 + (t&63); }
  else if(k < 576){ int t=k-320; srcrow = (5+(t>>6))*J.d + J.j0 + (t&63); }
  else            { int t=k-576; srcrow = (9+(t>>6))*J.d + J.j0 + (t&63); }
  J.dst[rel] = (_Float16)J.W[(size_t)srcrow*J.o + n];
}

// ---------------- fused MFMA layer GEMM: TRIPLE-buffered B, true counted vmcnt --
// (r9-proven: -40 us vs double-buffer under same-run conditions.) 3 LDS
// buffers, stage phase p+2 in phase p. End-of-phase wait vmcnt(K), K =
// a(p+1)+s(p+2)+a(p+2): proves stage(p+1) while leaving A(p+1) in flight
// across the barrier (landing enforced per-wave by the compiler's use-wait).

template<int NCH>
__global__ __launch_bounds__(256) void k_mfma_fused(
    const _Float16* __restrict__ actIn,
    const _Float16* __restrict__ aggs,          // [NCH][NN][256]
    const float* __restrict__ amp, const float* __restrict__ att,
    const _Float16* __restrict__ cs16, const _Float16* __restrict__ csh16,
    const _Float16* __restrict__ Wp, int o,     // [NCH][832*o]
    const float* __restrict__ bias,
    _Float16* __restrict__ out,                 // [NN][o], relu'd pre-BN
    float* __restrict__ colsum, float* __restrict__ colss,
    size_t aggN)
{
  constexpr int D = NCH * 64;
  constexpr int NPH = NCH * 9;
  __shared__ _Float16 Bsm[3][12*512];           // 3 x 12 KB triple buffer
  __shared__ float redS[64], redQ[64];
  int tid  = threadIdx.x;
  int wv   = tid >> 6;
  int lane = tid & 63;
  int mi   = lane & 15;
  int q    = lane >> 4;

  // bijective XCD swizzle (m204): same-y blocks land on same XCD's L2
  int T  = gridDim.x * gridDim.y;
  int n_ = blockIdx.y * gridDim.x + blockIdx.x;
  int qq = T >> 3, rr = T & 7, xc = n_ & 7, nl = n_ >> 3;
  int m_ = (xc < rr ? xc*(qq+1) : rr*(qq+1) + (xc-rr)*qq) + nl;
  int bx = m_ % gridDim.x;
  int by = m_ / gridDim.x;

  int m0   = by * 128 + wv * 32;
  int c0   = bx * 64;
  int ntiles = o >> 4;
  int nt0  = bx * 4;

  if(tid < 64){ redS[tid] = 0.f; redQ[tid] = 0.f; }

  int mrow[2];
  mrow[0] = min(m0 + mi,      NN-1);
  mrow[1] = min(m0 + 16 + mi, NN-1);
  _Float16 am16[2] = { (_Float16)amp[mrow[0]], (_Float16)amp[mrow[1]] };
  _Float16 at16[2] = { (_Float16)att[mrow[0]], (_Float16)att[mrow[1]] };
  const _Float16* hAb[2];
  const _Float16* agb[2];
  hAb[0] = actIn + (size_t)mrow[0]*D + q*8;
  hAb[1] = actIn + (size_t)mrow[1]*D + q*8;
  agb[0] = aggs + (size_t)mrow[0]*256 + q*8;
  agb[1] = aggs + (size_t)mrow[1]*256 + q*8;

  f4 acc[2][4] = {};

  // B-tile staging: tile ti lives at buf[ti*512 + lane*8]
  auto stageX = [&](_Float16* buf, int c){
    const _Float16* Wpc = Wp + (size_t)c*832*o;
    #pragma unroll
    for(int s = 0; s < 2; s++){
      int ti = wv*2 + s;
      int kb = ti >> 2, nn = ti & 3;
      gload_lds16(Wpc + (((size_t)kb*ntiles + nt0 + nn)*64 + lane)*8,
                  buf + ti*512);
    }
  };
  auto stageP = [&](_Float16* buf, int c, int idx){
    const _Float16* Wpc = Wp + (size_t)c*832*o;
    #pragma unroll
    for(int s = 0; s < 3; s++){
      int ti = wv*3 + s;
      int kj = ti >> 2, nn = ti & 3;
      int kb = (kj == 0 ? 2 : (kj == 1 ? 10 : 18)) + idx;
      gload_lds16(Wpc + (((size_t)kb*ntiles + nt0 + nn)*64 + lane)*8,
                  buf + ti*512);
    }
  };
  auto stagePh = [&](int p2){
    int c2 = p2 / 9, s2 = p2 % 9;
    _Float16* buf = &Bsm[p2 % 3][0];
    if(s2 == 0) stageX(buf, c2);
    else        stageP(buf, c2, s2 - 1);
  };

  // A-prefetch register banks (2-phase lead, statically indexed after unroll)
  h8 pA[2][4]; h8 pS[2][2]; h8 pH[2][2];
  auto loadA = [&](int ph2, int bank){
    if(ph2 >= NPH) return;
    int c = ph2 / 9, sub = ph2 % 9;
    if(sub == 0){
      #pragma unroll
      for(int kb = 0; kb < 2; kb++){
        pS[bank][kb] = *(const h8*)(cs16  + c*64 + kb*32 + q*8);
        pH[bank][kb] = *(const h8*)(csh16 + c*64 + kb*32 + q*8);
        #pragma unroll
        for(int t = 0; t < 2; t++)
          pA[bank][kb*2+t] = *(const h8*)(hAb[t] + c*64 + kb*32);
      }
    } else {
      int idx = sub - 1;
      #pragma unroll
      for(int t = 0; t < 2; t++)
        pA[bank][t] = *(const h8*)(agb[t] + (size_t)c*aggN + idx*32);
    }
  };

  // prologue: stage phases 0 and 1, pin, prefetch A(0) and A(1).
  // VMEM order: stage0(2), stage1(3), A0(8), A1(2) -> wait stage0 = vmcnt(13)
  stagePh(0);
  __builtin_amdgcn_sched_barrier(0);
  stagePh(1);
  __builtin_amdgcn_sched_barrier(0);
  loadA(0, 0);
  loadA(1, 1);
  __builtin_amdgcn_sched_barrier(0);
  asm volatile("s_waitcnt vmcnt(13)\n\ts_barrier" ::: "memory");

  #pragma unroll
  for(int ph = 0; ph < NPH; ph++){
    const int sub = ph % 9;                 // 0 = X phase, 1..8 = idx 0..7
    const int bank = ph & 1;
    _Float16* cur = &Bsm[ph % 3][0];

    // copy current-phase A fragments (compiler's use-wait lands A(ph) here;
    // per-wave, not a barrier -- other waves keep running)
    h8 cA[4]; h8 cS[2]; h8 cH[2];
    cA[0] = pA[bank][0]; cA[1] = pA[bank][1];
    if(sub == 0){
      cA[2] = pA[bank][2]; cA[3] = pA[bank][3];
      cS[0] = pS[bank][0]; cS[1] = pS[bank][1];
      cH[0] = pH[bank][0]; cH[1] = pH[bank][1];
    }

    // 1. stage phase p+2's B tiles (buffer (p+2)%3 was read in phase p-1;
    //    the end-of-(p-1) barrier released it)
    if(ph + 2 < NPH) stagePh(ph + 2);
    __builtin_amdgcn_sched_barrier(0);   // pin: stage ops precede A ops

    // 2. prefetch A for phase p+2 into this bank (2-phase lead)
    loadA(ph + 2, bank);

    // 3. compute current phase from LDS
    __builtin_amdgcn_s_setprio(1);
    if(sub == 0){
      #pragma unroll
      for(int kb = 0; kb < 2; kb++)
        #pragma unroll
        for(int t = 0; t < 2; t++){
          h8 ax = cA[kb*2+t]*cS[kb] + cH[kb];
          #pragma unroll
          for(int nn = 0; nn < 4; nn++)
            acc[t][nn] = __builtin_amdgcn_mfma_f32_16x16x32_f16(
                ax, *(const h8*)(cur + (kb*4+nn)*512 + lane*8), acc[t][nn], 0,0,0);
        }
    } else {
      #pragma unroll
      for(int t = 0; t < 2; t++){
        h8 apl = cA[t];
        h8 aam = apl * am16[t];
        h8 aat = apl * at16[t];
        #pragma unroll
        for(int nn = 0; nn < 4; nn++){
          acc[t][nn] = __builtin_amdgcn_mfma_f32_16x16x32_f16(
              apl, *(const h8*)(cur + (0*4+nn)*512 + lane*8), acc[t][nn], 0,0,0);
          acc[t][nn] = __builtin_amdgcn_mfma_f32_16x16x32_f16(
              aam, *(const h8*)(cur + (4+nn)*512 + lane*8), acc[t][nn], 0,0,0);
          acc[t][nn] = __builtin_amdgcn_mfma_f32_16x16x32_f16(
              aat, *(const h8*)(cur + (8+nn)*512 + lane*8), acc[t][nn], 0,0,0);
        }
      }
    }
    __builtin_amdgcn_s_setprio(0);

    // 4. counted barrier: K = a(p+1) + s(p+2) + a(p+2) leaves A(p+1),
    //    stage(p+2), A(p+2) in flight; drains through stage(p+1).
    if(ph + 1 < NPH){
      const bool x1   = ((ph + 1) % 9) == 0;
      const bool has2 = (ph + 2) < NPH;
      const bool x2   = has2 && (((ph + 2) % 9) == 0);
      const int K = (x1 ? 8 : 2) + (has2 ? ((x2 ? 2 : 3) + (x2 ? 8 : 2)) : 0);
      if(K == 13)      asm volatile("s_waitcnt vmcnt(13)\n\ts_barrier" ::: "memory");
      else if(K == 12) asm volatile("s_waitcnt vmcnt(12)\n\ts_barrier" ::: "memory");
      else if(K == 7)  asm volatile("s_waitcnt vmcnt(7)\n\ts_barrier" ::: "memory");
      else             asm volatile("s_waitcnt vmcnt(2)\n\ts_barrier" ::: "memory");
    }
  }

  __syncthreads();   // redS/redQ zero-init visible; full drain before epilogue

  // ---- epilogue: +bias, ReLU, store, stats via q-fold shuffles ----
  #pragma unroll
  for(int nn = 0; nn < 4; nn++){
    int n = c0 + nn*16 + mi;
    float bv = bias[n];
    float ps = 0.f, pq = 0.f;
    #pragma unroll
    for(int t = 0; t < 2; t++){
      #pragma unroll
      for(int r = 0; r < 4; r++){
        int m = m0 + t*16 + q*4 + r;
        if(m < NN){
          float v = fmaxf(bv + acc[t][nn][r], 0.f);
          out[(size_t)m*o + n] = (_Float16)v;
          ps += v; pq += v*v;
        }
      }
    }
    ps += __shfl_xor(ps, 16); pq += __shfl_xor(pq, 16);
    ps += __shfl_xor(ps, 32); pq += __shfl_xor(pq, 32);
    if(q == 0){
      atomicAdd(&redS[nn*16 + mi], ps);
      atomicAdd(&redQ[nn*16 + mi], pq);
    }
  }
  __syncthreads();
  if(tid < 64){
    atomicAdd(&colsum[c0 + tid], redS[tid]);
    atomicAdd(&colss[c0 + tid],  redQ[tid]);
  }
}

// ---------------- classifier (applies final BN affine on load) ----------------

__global__ __launch_bounds__(256) void k_cls(const _Float16* __restrict__ h,
    const float* __restrict__ cs, const float* __restrict__ csh,
    const float* __restrict__ Wc, const float* __restrict__ bc,
    float* __restrict__ out){
  __shared__ float w[640];
  __shared__ float bb[16];
  __shared__ float sca[64], shb[64];
  int tid = threadIdx.x;
  for(int i = tid; i < 640; i += 256) w[i] = Wc[i];
  if(tid < 10) bb[tid] = bc[tid];
  if(tid < 64){ sca[tid] = cs[tid]; shb[tid] = csh[tid]; }
  __syncthreads();
  int idx = blockIdx.x*256 + tid;
  int n = idx >> 4;
  int c = idx & 15;
  if(n < NN && c < 10){
    float acc = bb[c];
    const _Float16* hp = h + (size_t)n*64;
    #pragma unroll
    for(int k = 0; k < 64; k++)
      acc += ((float)hp[k]*sca[k] + shb[k]) * w[k*10 + c];
    out[(size_t)n*10 + c] = acc;
  }
}

// ---------------- launch ----------------

extern "C" void kernel_launch(void* const* d_in, const int* in_sizes, int n_in,
                              void* d_out, int out_size, void* d_ws, size_t ws_size,
                              hipStream_t stream){
  const float* x = (const float*)d_in[0];
  const int* edge = (const int*)d_in[1];
  const int* esrc = edge;
  const int* edst = edge + NE;
  const float* W[4]  = {(const float*)d_in[2],  (const float*)d_in[6],
                        (const float*)d_in[10], (const float*)d_in[14]};
  const float* bb[4] = {(const float*)d_in[3],  (const float*)d_in[7],
                        (const float*)d_in[11], (const float*)d_in[15]};
  const float* gm[4] = {(const float*)d_in[4],  (const float*)d_in[8],
                        (const float*)d_in[12], (const float*)d_in[16]};
  const float* bt[4] = {(const float*)d_in[5],  (const float*)d_in[9],
                        (const float*)d_in[13], (const float*)d_in[17]};
  const float* Wc = (const float*)d_in[18];
  const float* bc = (const float*)d_in[19];
  (void)in_sizes; (void)n_in; (void)out_size; (void)ws_size;

  // workspace carve (~158 MB; proven-safe envelope)
  char* p = (char*)d_ws;
  auto alloc = [&](size_t bytes)->char*{
    char* r = p; p += (bytes + 255) & ~(size_t)255; return r;
  };
  _Float16* act0 = (_Float16*)alloc((size_t)NN*256*2);   // 25.6 MB
  _Float16* act1 = (_Float16*)alloc((size_t)NN*256*2);   // 25.6 MB
  _Float16* aggs = (_Float16*)alloc((size_t)4*NN*256*2); // 102.4 MB: [chunk][N][256]
  int*   deg    = (int*)  alloc((size_t)NN*4);
  float* logdeg = (float*)alloc((size_t)NN*4);
  float* amp    = (float*)alloc((size_t)NN*4);
  float* att    = (float*)alloc((size_t)NN*4);
  int*   rowptr = (int*)  alloc((size_t)(NN+1)*4);
  int*   cursor = (int*)  alloc((size_t)NN*4);
  int*   colidx = (int*)  alloc((size_t)NE*4);
  int*   bsum   = (int*)  alloc((size_t)(NB+1)*4);
  float* colsumL= (float*)alloc(4*256*4);   // per-layer BN partials
  float* colssL = (float*)alloc(4*256*4);
  float* dsum   = (float*)alloc(256);
  // BN coefficient double-buffers (fp32 + fp16)
  float*    csA  = (float*)   alloc(256*4);
  float*    cshA = (float*)   alloc(256*4);
  float*    csB  = (float*)   alloc(256*4);
  float*    cshB = (float*)   alloc(256*4);
  _Float16* cs16A  = (_Float16*)alloc(256*2);
  _Float16* csh16A = (_Float16*)alloc(256*2);
  _Float16* cs16B  = (_Float16*)alloc(256*2);
  _Float16* csh16B = (_Float16*)alloc(256*2);

  const int din[4]  = {64, 128, 256, 128};
  const int dto[4]  = {128, 256, 128, 64};
  const size_t aggN = (size_t)NN*256;      // halves per chunk slab
  _Float16* WpL[4];
  PackArgs pa; int pj = 0, poff = 0;
  for(int l = 0; l < 4; l++){
    int nch = din[l]/64;
    WpL[l] = (_Float16*)alloc((size_t)nch*832*dto[l]*2);
    for(int c = 0; c < nch; c++){
      pa.job[pj] = { W[l], WpL[l] + (size_t)c*832*dto[l], din[l], dto[l], c*64, poff };
      poff += 832*dto[l]; pj++;
    }
  }
  pa.total = poff;

  hipMemsetAsync(deg, 0, (size_t)NN*4, stream);
  hipMemsetAsync(dsum, 0, 4, stream);
  hipMemsetAsync(colsumL, 0, 4*256*4, stream);
  hipMemsetAsync(colssL,  0, 4*256*4, stream);

  k_pack_all<<<(pa.total+255)/256, 256, 0, stream>>>(pa);
  k_deg     <<<(NE+255)/256, 256, 0, stream>>>(edst, deg);
  k_logdeg  <<<(NN+255)/256, 256, 0, stream>>>(deg, logdeg, dsum);
  k_scalers <<<(NN+255)/256, 256, 0, stream>>>(logdeg, dsum, amp, att);
  k_scan1   <<<NB, 1024, 0, stream>>>(deg, rowptr, bsum);
  k_scan2   <<<1, 64, 0, stream>>>(bsum);
  k_scan3   <<<(NN+256)/256, 256, 0, stream>>>(rowptr, cursor, bsum);
  k_fill    <<<(NE+255)/256, 256, 0, stream>>>(esrc, edst, cursor, colidx);
  k_cvtx    <<<(NN*64+255)/256, 256, 0, stream>>>(x, act0);
  k_coef_id <<<1, 256, 0, stream>>>(csA, cshA, cs16A, csh16A);

  _Float16* actIn = act0;  _Float16* actOut = act1;
  float *csI = csA, *cshI = cshA, *csO = csB, *cshO = cshB;
  _Float16 *cs16I = cs16A, *csh16I = csh16A, *cs16O = cs16B, *csh16O = csh16B;

  for(int l = 0; l < 4; l++){
    int d = din[l], o = dto[l];
    int npb = (64 / (d >> 3)) * 4;          // nodes per block in k_agg8
    int nagg = (NN + npb - 1) / npb;
    dim3 g(o/64, (NN+127)/128);
    float* csum = colsumL + l*256;
    float* csq  = colssL + l*256;
    switch(d){
      case 64:
        k_agg8<64><<<nagg, 256, 0, stream>>>(actIn, rowptr, colidx, csI, cshI, aggs, aggN);
        k_mfma_fused<1><<<g, 256, 0, stream>>>(actIn, aggs, amp, att, cs16I, csh16I,
                                               WpL[l], o, bb[l], actOut, csum, csq, aggN);
        break;
      case 128:
        k_agg8<128><<<nagg, 256, 0, stream>>>(actIn, rowptr, colidx, csI, cshI, aggs, aggN);
        k_mfma_fused<2><<<g, 256, 0, stream>>>(actIn, aggs, amp, att, cs16I, csh16I,
                                               WpL[l], o, bb[l], actOut, csum, csq, aggN);
        break;
      default:
        k_agg8<256><<<nagg, 256, 0, stream>>>(actIn, rowptr, colidx, csI, cshI, aggs, aggN);
        k_mfma_fused<4><<<g, 256, 0, stream>>>(actIn, aggs, amp, att, cs16I, csh16I,
                                               WpL[l], o, bb[l], actOut, csum, csq, aggN);
        break;
    }
    k_bn_coef<<<1, 256, 0, stream>>>(csum, csq, gm[l], bt[l], o,
                                     csO, cshO, cs16O, csh16O);
    // swap activation and coefficient buffers
    _Float16* ta = actIn; actIn = actOut; actOut = ta;
    float* tf;
    tf = csI;  csI = csO;  csO = tf;
    tf = cshI; cshI = cshO; cshO = tf;
    _Float16* th;
    th = cs16I;  cs16I = cs16O;  cs16O = th;
    th = csh16I; csh16I = csh16O; csh16O = th;
  }
  k_cls<<<(NN*16+255)/256, 256, 0, stream>>>(actIn, csI, cshI, Wc, bc, (float*)d_out);
}

// Round 11
// 649.328 us; speedup vs baseline: 1.1544x; 1.0038x over previous
//
#include <hip/hip_runtime.h>
#include <hip/hip_bf16.h>

#define NN 50000
#define NE 800000
#define EPSV 1e-5f
#define NB 49   // scan blocks: ceil(NN/1024)

typedef _Float16 h8 __attribute__((ext_vector_type(8)));
typedef float    f4 __attribute__((ext_vector_type(4)));

#define AS1 __attribute__((address_space(1)))
#define AS3 __attribute__((address_space(3)))

__device__ __forceinline__ void gload_lds16(const _Float16* g, _Float16* l){
  __builtin_amdgcn_global_load_lds((const AS1 void*)g, (AS3 void*)l, 16, 0, 0);
}

// ---------------- graph preprocessing ----------------

__global__ void k_deg(const int* __restrict__ dst, int* __restrict__ deg){
  int e = blockIdx.x*blockDim.x + threadIdx.x;
  if(e < NE) atomicAdd(&deg[dst[e]], 1);
}

__global__ void k_logdeg(const int* __restrict__ deg, float* __restrict__ logdeg,
                         float* __restrict__ dsum){
  int i = blockIdx.x*blockDim.x + threadIdx.x;
  float v = 0.f;
  if(i < NN){ v = log1pf((float)deg[i]); logdeg[i] = v; }
  __shared__ float sh[256];
  sh[threadIdx.x] = v; __syncthreads();
  for(int off=128; off>0; off>>=1){
    if(threadIdx.x < off) sh[threadIdx.x] += sh[threadIdx.x+off];
    __syncthreads();
  }
  if(threadIdx.x == 0) atomicAdd(dsum, sh[0]);
}

__global__ void k_scalers(const float* __restrict__ logdeg, const float* __restrict__ dsum,
                          float* __restrict__ amp, float* __restrict__ att){
  int i = blockIdx.x*blockDim.x + threadIdx.x;
  if(i >= NN) return;
  float delta = dsum[0] / (float)NN;
  float ld = logdeg[i];
  amp[i] = ld / delta;
  att[i] = (ld > 0.f) ? (delta / fmaxf(ld, 1e-6f)) : 1.f;
}

// 3-phase parallel exclusive scan of deg -> rowptr (+cursor copy)
__global__ void k_scan1(const int* __restrict__ deg, int* __restrict__ rowptr,
                        int* __restrict__ bsum){
  __shared__ int buf[1024];
  int tid = threadIdx.x;
  int i = blockIdx.x*1024 + tid;
  int v = (i < NN) ? deg[i] : 0;
  buf[tid] = v; __syncthreads();
  for(int off=1; off<1024; off<<=1){
    int t = (tid >= off) ? buf[tid-off] : 0;
    __syncthreads();
    buf[tid] += t;
    __syncthreads();
  }
  if(i < NN) rowptr[i] = buf[tid] - v;
  if(tid == 1023) bsum[blockIdx.x] = buf[1023];
}

__global__ void k_scan2(int* __restrict__ bsum){
  if(threadIdx.x == 0){
    int s = 0;
    for(int b = 0; b < NB; b++){ int t = bsum[b]; bsum[b] = s; s += t; }
    bsum[NB] = s;
  }
}

__global__ void k_scan3(int* __restrict__ rowptr, int* __restrict__ cursor,
                        const int* __restrict__ bsum){
  int i = blockIdx.x*256 + threadIdx.x;
  if(i < NN){
    int v = rowptr[i] + bsum[i >> 10];
    rowptr[i] = v; cursor[i] = v;
  }
  if(i == NN) rowptr[NN] = bsum[NB];
}

__global__ void k_fill(const int* __restrict__ src, const int* __restrict__ dst,
                       int* __restrict__ cursor, int* __restrict__ colidx){
  int e = blockIdx.x*blockDim.x + threadIdx.x;
  if(e < NE){
    int pos = atomicAdd(&cursor[dst[e]], 1);
    colidx[pos] = src[e];
  }
}

__global__ void k_cvtx(const float* __restrict__ x, _Float16* __restrict__ act){
  int i = blockIdx.x*256 + threadIdx.x;
  if(i < NN*64) act[i] = (_Float16)x[i];
}

// identity BN coefficients for layer 1
__global__ void k_coef_id(float* __restrict__ cs, float* __restrict__ csh,
                          _Float16* __restrict__ cs16, _Float16* __restrict__ csh16){
  int c = threadIdx.x;
  cs[c] = 1.f; csh[c] = 0.f;
  cs16[c] = (_Float16)1.f; csh16[c] = (_Float16)0.f;
}

// BN coefficients from stats: v' = a*v + b with a=inv*gamma, b=beta-mean*a
__global__ void k_bn_coef(const float* __restrict__ colsum, const float* __restrict__ colss,
                          const float* __restrict__ gamma, const float* __restrict__ beta,
                          int dout, float* __restrict__ cs, float* __restrict__ csh,
                          _Float16* __restrict__ cs16, _Float16* __restrict__ csh16){
  int c = threadIdx.x;
  if(c >= dout) return;
  float mean = colsum[c] / (float)NN;
  float var  = colss[c] / (float)NN - mean*mean;
  float inv  = rsqrtf(fmaxf(var, 0.f) + EPSV);
  float a = inv * gamma[c];
  float b = beta[c] - mean * a;
  cs[c] = a; csh[c] = b;
  cs16[c] = (_Float16)a; csh16[c] = (_Float16)b;
}

// ---------------- aggregation: COLUMN-CHUNKED gather (L2-locality) -------------
// Gather is cache-bound at ~4.2 TB/s: working set (12.8-25.6 MB) >> 4 MB
// per-XCD L2 -> ~16% hit. Chunking D into 64-col slices with chunk as the
// SLOW blockIdx axis (blocks dispatch ~in order -> chunk-serial) shrinks the
// gathered footprint to 6.4 MB/chunk. Same total bytes/VALU; 128B-aligned
// coalesced segments. Per-chunk geometry = the D=64 kernel: 8 lanes/node,
// 8 nodes/wave, 32 nodes/block. Writeout maps onto the per-chunk aggs slab.

template<int DFULL>
__global__ __launch_bounds__(256) void k_agg8c(
    const _Float16* __restrict__ act,
    const int* __restrict__ rowptr, const int* __restrict__ colidx,
    const float* __restrict__ cs, const float* __restrict__ csh,
    _Float16* __restrict__ aggs, size_t aggN)
{
  constexpr int NPC = (NN + 31) >> 5;   // node-blocks per chunk
  int chunk = blockIdx.x / NPC;
  int nb    = blockIdx.x - chunk*NPC;
  int wv = threadIdx.x >> 6, lane = threadIdx.x & 63;
  int n  = nb*32 + wv*8 + (lane >> 3);
  int cl = (lane & 7) * 8;              // col within chunk [0,64)
  int cg = chunk*64 + cl;               // global col
  if(n >= NN) return;
  int beg = rowptr[n], end = rowptr[n+1];
  const _Float16* hp = act + cg;

  float s[8], q[8], mn[8], mx[8];
  #pragma unroll
  for(int j = 0; j < 8; j++){ s[j]=0.f; q[j]=0.f; mn[j]=INFINITY; mx[j]=-INFINITY; }

#define ACC8(v) { _Pragma("unroll") for(int j=0;j<8;j++){ float a=(float)(v)[j]; \
    s[j]+=a; q[j]+=a*a; mn[j]=fminf(mn[j],a); mx[j]=fmaxf(mx[j],a); } }

  int e = beg;
  for(; e+8 <= end; e+=8){
    int i0=colidx[e],   i1=colidx[e+1], i2=colidx[e+2], i3=colidx[e+3];
    int i4=colidx[e+4], i5=colidx[e+5], i6=colidx[e+6], i7=colidx[e+7];
    h8 v0 = *(const h8*)(hp + (size_t)i0*DFULL);
    h8 v1 = *(const h8*)(hp + (size_t)i1*DFULL);
    h8 v2 = *(const h8*)(hp + (size_t)i2*DFULL);
    h8 v3 = *(const h8*)(hp + (size_t)i3*DFULL);
    h8 v4 = *(const h8*)(hp + (size_t)i4*DFULL);
    h8 v5 = *(const h8*)(hp + (size_t)i5*DFULL);
    h8 v6 = *(const h8*)(hp + (size_t)i6*DFULL);
    h8 v7 = *(const h8*)(hp + (size_t)i7*DFULL);
    ACC8(v0) ACC8(v1) ACC8(v2) ACC8(v3) ACC8(v4) ACC8(v5) ACC8(v6) ACC8(v7)
  }
  for(; e+4 <= end; e+=4){
    int i0=colidx[e], i1=colidx[e+1], i2=colidx[e+2], i3=colidx[e+3];
    h8 v0 = *(const h8*)(hp + (size_t)i0*DFULL);
    h8 v1 = *(const h8*)(hp + (size_t)i1*DFULL);
    h8 v2 = *(const h8*)(hp + (size_t)i2*DFULL);
    h8 v3 = *(const h8*)(hp + (size_t)i3*DFULL);
    ACC8(v0) ACC8(v1) ACC8(v2) ACC8(v3)
  }
  for(; e < end; e++){
    h8 v = *(const h8*)(hp + (size_t)colidx[e]*DFULL);
    ACC8(v)
  }
#undef ACC8

  float cnt = (end>beg) ? (float)(end-beg) : 1.f;
  h8 vm, vn, vx, vs;
  #pragma unroll
  for(int j = 0; j < 8; j++){
    float a = cs[cg+j], b = csh[cg+j];
    float mean_r = s[j]/cnt;
    float var_r  = fmaxf(q[j]/cnt - mean_r*mean_r, 0.f);
    float meanp = a*mean_r + b;
    float mnp = (a >= 0.f) ? a*mn[j]+b : a*mx[j]+b;
    float mxp = (a >= 0.f) ? a*mx[j]+b : a*mn[j]+b;
    float sdp = sqrtf(a*a*var_r + EPSV);
    if(end <= beg){ meanp = 0.f; mnp = 0.f; mxp = 0.f; sdp = sqrtf(EPSV); }
    vm[j] = (_Float16)meanp; vn[j] = (_Float16)mnp;
    vx[j] = (_Float16)mxp;   vs[j] = (_Float16)sdp;
  }

  _Float16* dst = aggs + (size_t)chunk*aggN + (size_t)n*256 + cl;
  *(h8*)(dst)       = vm;
  *(h8*)(dst + 64)  = vn;
  *(h8*)(dst + 128) = vx;
  *(h8*)(dst + 192) = vs;
}

// ---------------- fused W pre-pack (all layers/chunks, one kernel) ----------------

struct PackJob { const float* W; _Float16* dst; int d, o, j0, start; };
struct PackArgs { PackJob job[9]; int total; };

__global__ void k_pack_all(PackArgs a){
  int idx = blockIdx.x*256 + threadIdx.x;
  if(idx >= a.total) return;
  int ji = 0;
  while(ji < 8 && idx >= a.job[ji+1].start) ji++;
  PackJob J = a.job[ji];
  int rel = idx - J.start;
  int j    = rel & 7;
  int lane = (rel >> 3) & 63;
  int rem  = rel >> 9;
  int ntiles = J.o >> 4;
  int kb = rem / ntiles;
  int nt = rem - kb*ntiles;
  int k = kb*32 + (lane>>4)*8 + j;
  int n = nt*16 + (lane&15);
  int srcrow;
  if(k < 64)       srcrow = J.j0 + k;
  else if(k < 320){ int t=k-64;  srcrow = (1+(t>>6))*J.d + J.j0 + (t&63); }
  else if(k < 576){ int t=k-320; srcrow = (5+(t>>6))*J.d + J.j0 + (t&63); }
  else            { int t=k-576; srcrow = (9+(t>>6))*J.d + J.j0 + (t&63); }
  J.dst[rel] = (_Float16)J.W[(size_t)srcrow*J.o + n];
}

// ---------------- fused MFMA layer GEMM: TRIPLE-buffered B, true counted vmcnt --
// (r9/r10-proven.) 3 LDS buffers, stage phase p+2 in phase p. End-of-phase
// wait vmcnt(K), K = a(p+1)+s(p+2)+a(p+2): proves stage(p+1) while leaving
// A(p+1) in flight across the barrier.

template<int NCH>
__global__ __launch_bounds__(256) void k_mfma_fused(
    const _Float16* __restrict__ actIn,
    const _Float16* __restrict__ aggs,          // [NCH][NN][256]
    const float* __restrict__ amp, const float* __restrict__ att,
    const _Float16* __restrict__ cs16, const _Float16* __restrict__ csh16,
    const _Float16* __restrict__ Wp, int o,     // [NCH][832*o]
    const float* __restrict__ bias,
    _Float16* __restrict__ out,                 // [NN][o], relu'd pre-BN
    float* __restrict__ colsum, float* __restrict__ colss,
    size_t aggN)
{
  constexpr int D = NCH * 64;
  constexpr int NPH = NCH * 9;
  __shared__ _Float16 Bsm[3][12*512];           // 3 x 12 KB triple buffer
  __shared__ float redS[64], redQ[64];
  int tid  = threadIdx.x;
  int wv   = tid >> 6;
  int lane = tid & 63;
  int mi   = lane & 15;
  int q    = lane >> 4;

  // bijective XCD swizzle (m204): same-y blocks land on same XCD's L2
  int T  = gridDim.x * gridDim.y;
  int n_ = blockIdx.y * gridDim.x + blockIdx.x;
  int qq = T >> 3, rr = T & 7, xc = n_ & 7, nl = n_ >> 3;
  int m_ = (xc < rr ? xc*(qq+1) : rr*(qq+1) + (xc-rr)*qq) + nl;
  int bx = m_ % gridDim.x;
  int by = m_ / gridDim.x;

  int m0   = by * 128 + wv * 32;
  int c0   = bx * 64;
  int ntiles = o >> 4;
  int nt0  = bx * 4;

  if(tid < 64){ redS[tid] = 0.f; redQ[tid] = 0.f; }

  int mrow[2];
  mrow[0] = min(m0 + mi,      NN-1);
  mrow[1] = min(m0 + 16 + mi, NN-1);
  _Float16 am16[2] = { (_Float16)amp[mrow[0]], (_Float16)amp[mrow[1]] };
  _Float16 at16[2] = { (_Float16)att[mrow[0]], (_Float16)att[mrow[1]] };
  const _Float16* hAb[2];
  const _Float16* agb[2];
  hAb[0] = actIn + (size_t)mrow[0]*D + q*8;
  hAb[1] = actIn + (size_t)mrow[1]*D + q*8;
  agb[0] = aggs + (size_t)mrow[0]*256 + q*8;
  agb[1] = aggs + (size_t)mrow[1]*256 + q*8;

  f4 acc[2][4] = {};

  // B-tile staging: tile ti lives at buf[ti*512 + lane*8]
  auto stageX = [&](_Float16* buf, int c){
    const _Float16* Wpc = Wp + (size_t)c*832*o;
    #pragma unroll
    for(int s = 0; s < 2; s++){
      int ti = wv*2 + s;
      int kb = ti >> 2, nn = ti & 3;
      gload_lds16(Wpc + (((size_t)kb*ntiles + nt0 + nn)*64 + lane)*8,
                  buf + ti*512);
    }
  };
  auto stageP = [&](_Float16* buf, int c, int idx){
    const _Float16* Wpc = Wp + (size_t)c*832*o;
    #pragma unroll
    for(int s = 0; s < 3; s++){
      int ti = wv*3 + s;
      int kj = ti >> 2, nn = ti & 3;
      int kb = (kj == 0 ? 2 : (kj == 1 ? 10 : 18)) + idx;
      gload_lds16(Wpc + (((size_t)kb*ntiles + nt0 + nn)*64 + lane)*8,
                  buf + ti*512);
    }
  };
  auto stagePh = [&](int p2){
    int c2 = p2 / 9, s2 = p2 % 9;
    _Float16* buf = &Bsm[p2 % 3][0];
    if(s2 == 0) stageX(buf, c2);
    else        stageP(buf, c2, s2 - 1);
  };

  // A-prefetch register banks (2-phase lead, statically indexed after unroll)
  h8 pA[2][4]; h8 pS[2][2]; h8 pH[2][2];
  auto loadA = [&](int ph2, int bank){
    if(ph2 >= NPH) return;
    int c = ph2 / 9, sub = ph2 % 9;
    if(sub == 0){
      #pragma unroll
      for(int kb = 0; kb < 2; kb++){
        pS[bank][kb] = *(const h8*)(cs16  + c*64 + kb*32 + q*8);
        pH[bank][kb] = *(const h8*)(csh16 + c*64 + kb*32 + q*8);
        #pragma unroll
        for(int t = 0; t < 2; t++)
          pA[bank][kb*2+t] = *(const h8*)(hAb[t] + c*64 + kb*32);
      }
    } else {
      int idx = sub - 1;
      #pragma unroll
      for(int t = 0; t < 2; t++)
        pA[bank][t] = *(const h8*)(agb[t] + (size_t)c*aggN + idx*32);
    }
  };

  // prologue: stage phases 0 and 1, pin, prefetch A(0) and A(1).
  // VMEM order: stage0(2), stage1(3), A0(8), A1(2) -> wait stage0 = vmcnt(13)
  stagePh(0);
  __builtin_amdgcn_sched_barrier(0);
  stagePh(1);
  __builtin_amdgcn_sched_barrier(0);
  loadA(0, 0);
  loadA(1, 1);
  __builtin_amdgcn_sched_barrier(0);
  asm volatile("s_waitcnt vmcnt(13)\n\ts_barrier" ::: "memory");

  #pragma unroll
  for(int ph = 0; ph < NPH; ph++){
    const int sub = ph % 9;                 // 0 = X phase, 1..8 = idx 0..7
    const int bank = ph & 1;
    _Float16* cur = &Bsm[ph % 3][0];

    // copy current-phase A fragments (compiler's use-wait lands A(ph) here;
    // per-wave, not a barrier -- other waves keep running)
    h8 cA[4]; h8 cS[2]; h8 cH[2];
    cA[0] = pA[bank][0]; cA[1] = pA[bank][1];
    if(sub == 0){
      cA[2] = pA[bank][2]; cA[3] = pA[bank][3];
      cS[0] = pS[bank][0]; cS[1] = pS[bank][1];
      cH[0] = pH[bank][0]; cH[1] = pH[bank][1];
    }

    // 1. stage phase p+2's B tiles (buffer (p+2)%3 was read in phase p-1;
    //    the end-of-(p-1) barrier released it)
    if(ph + 2 < NPH) stagePh(ph + 2);
    __builtin_amdgcn_sched_barrier(0);   // pin: stage ops precede A ops

    // 2. prefetch A for phase p+2 into this bank (2-phase lead)
    loadA(ph + 2, bank);

    // 3. compute current phase from LDS
    __builtin_amdgcn_s_setprio(1);
    if(sub == 0){
      #pragma unroll
      for(int kb = 0; kb < 2; kb++)
        #pragma unroll
        for(int t = 0; t < 2; t++){
          h8 ax = cA[kb*2+t]*cS[kb] + cH[kb];
          #pragma unroll
          for(int nn = 0; nn < 4; nn++)
            acc[t][nn] = __builtin_amdgcn_mfma_f32_16x16x32_f16(
                ax, *(const h8*)(cur + (kb*4+nn)*512 + lane*8), acc[t][nn], 0,0,0);
        }
    } else {
      #pragma unroll
      for(int t = 0; t < 2; t++){
        h8 apl = cA[t];
        h8 aam = apl * am16[t];
        h8 aat = apl * at16[t];
        #pragma unroll
        for(int nn = 0; nn < 4; nn++){
          acc[t][nn] = __builtin_amdgcn_mfma_f32_16x16x32_f16(
              apl, *(const h8*)(cur + (0*4+nn)*512 + lane*8), acc[t][nn], 0,0,0);
          acc[t][nn] = __builtin_amdgcn_mfma_f32_16x16x32_f16(
              aam, *(const h8*)(cur + (4+nn)*512 + lane*8), acc[t][nn], 0,0,0);
          acc[t][nn] = __builtin_amdgcn_mfma_f32_16x16x32_f16(
              aat, *(const h8*)(cur + (8+nn)*512 + lane*8), acc[t][nn], 0,0,0);
        }
      }
    }
    __builtin_amdgcn_s_setprio(0);

    // 4. counted barrier: K = a(p+1) + s(p+2) + a(p+2) leaves A(p+1),
    //    stage(p+2), A(p+2) in flight; drains through stage(p+1).
    if(ph + 1 < NPH){
      const bool x1   = ((ph + 1) % 9) == 0;
      const bool has2 = (ph + 2) < NPH;
      const bool x2   = has2 && (((ph + 2) % 9) == 0);
      const int K = (x1 ? 8 : 2) + (has2 ? ((x2 ? 2 : 3) + (x2 ? 8 : 2)) : 0);
      if(K == 13)      asm volatile("s_waitcnt vmcnt(13)\n\ts_barrier" ::: "memory");
      else if(K == 12) asm volatile("s_waitcnt vmcnt(12)\n\ts_barrier" ::: "memory");
      else if(K == 7)  asm volatile("s_waitcnt vmcnt(7)\n\ts_barrier" ::: "memory");
      else             asm volatile("s_waitcnt vmcnt(2)\n\ts_barrier" ::: "memory");
    }
  }

  __syncthreads();   // redS/redQ zero-init visible; full drain before epilogue

  // ---- epilogue: +bias, ReLU, store, stats via q-fold shuffles ----
  #pragma unroll
  for(int nn = 0; nn < 4; nn++){
    int n = c0 + nn*16 + mi;
    float bv = bias[n];
    float ps = 0.f, pq = 0.f;
    #pragma unroll
    for(int t = 0; t < 2; t++){
      #pragma unroll
      for(int r = 0; r < 4; r++){
        int m = m0 + t*16 + q*4 + r;
        if(m < NN){
          float v = fmaxf(bv + acc[t][nn][r], 0.f);
          out[(size_t)m*o + n] = (_Float16)v;
          ps += v; pq += v*v;
        }
      }
    }
    ps += __shfl_xor(ps, 16); pq += __shfl_xor(pq, 16);
    ps += __shfl_xor(ps, 32); pq += __shfl_xor(pq, 32);
    if(q == 0){
      atomicAdd(&redS[nn*16 + mi], ps);
      atomicAdd(&redQ[nn*16 + mi], pq);
    }
  }
  __syncthreads();
  if(tid < 64){
    atomicAdd(&colsum[c0 + tid], redS[tid]);
    atomicAdd(&colss[c0 + tid],  redQ[tid]);
  }
}

// ---------------- classifier (applies final BN affine on load) ----------------

__global__ __launch_bounds__(256) void k_cls(const _Float16* __restrict__ h,
    const float* __restrict__ cs, const float* __restrict__ csh,
    const float* __restrict__ Wc, const float* __restrict__ bc,
    float* __restrict__ out){
  __shared__ float w[640];
  __shared__ float bb[16];
  __shared__ float sca[64], shb[64];
  int tid = threadIdx.x;
  for(int i = tid; i < 640; i += 256) w[i] = Wc[i];
  if(tid < 10) bb[tid] = bc[tid];
  if(tid < 64){ sca[tid] = cs[tid]; shb[tid] = csh[tid]; }
  __syncthreads();
  int idx = blockIdx.x*256 + tid;
  int n = idx >> 4;
  int c = idx & 15;
  if(n < NN && c < 10){
    float acc = bb[c];
    const _Float16* hp = h + (size_t)n*64;
    #pragma unroll
    for(int k = 0; k < 64; k++)
      acc += ((float)hp[k]*sca[k] + shb[k]) * w[k*10 + c];
    out[(size_t)n*10 + c] = acc;
  }
}

// ---------------- launch ----------------

extern "C" void kernel_launch(void* const* d_in, const int* in_sizes, int n_in,
                              void* d_out, int out_size, void* d_ws, size_t ws_size,
                              hipStream_t stream){
  const float* x = (const float*)d_in[0];
  const int* edge = (const int*)d_in[1];
  const int* esrc = edge;
  const int* edst = edge + NE;
  const float* W[4]  = {(const float*)d_in[2],  (const float*)d_in[6],
                        (const float*)d_in[10], (const float*)d_in[14]};
  const float* bb[4] = {(const float*)d_in[3],  (const float*)d_in[7],
                        (const float*)d_in[11], (const float*)d_in[15]};
  const float* gm[4] = {(const float*)d_in[4],  (const float*)d_in[8],
                        (const float*)d_in[12], (const float*)d_in[16]};
  const float* bt[4] = {(const float*)d_in[5],  (const float*)d_in[9],
                        (const float*)d_in[13], (const float*)d_in[17]};
  const float* Wc = (const float*)d_in[18];
  const float* bc = (const float*)d_in[19];
  (void)in_sizes; (void)n_in; (void)out_size; (void)ws_size;

  // workspace carve (~158 MB; proven-safe envelope)
  char* p = (char*)d_ws;
  auto alloc = [&](size_t bytes)->char*{
    char* r = p; p += (bytes + 255) & ~(size_t)255; return r;
  };
  _Float16* act0 = (_Float16*)alloc((size_t)NN*256*2);   // 25.6 MB
  _Float16* act1 = (_Float16*)alloc((size_t)NN*256*2);   // 25.6 MB
  _Float16* aggs = (_Float16*)alloc((size_t)4*NN*256*2); // 102.4 MB: [chunk][N][256]
  int*   deg    = (int*)  alloc((size_t)NN*4);
  float* logdeg = (float*)alloc((size_t)NN*4);
  float* amp    = (float*)alloc((size_t)NN*4);
  float* att    = (float*)alloc((size_t)NN*4);
  int*   rowptr = (int*)  alloc((size_t)(NN+1)*4);
  int*   cursor = (int*)  alloc((size_t)NN*4);
  int*   colidx = (int*)  alloc((size_t)NE*4);
  int*   bsum   = (int*)  alloc((size_t)(NB+1)*4);
  float* colsumL= (float*)alloc(4*256*4);   // per-layer BN partials
  float* colssL = (float*)alloc(4*256*4);
  float* dsum   = (float*)alloc(256);
  // BN coefficient double-buffers (fp32 + fp16)
  float*    csA  = (float*)   alloc(256*4);
  float*    cshA = (float*)   alloc(256*4);
  float*    csB  = (float*)   alloc(256*4);
  float*    cshB = (float*)   alloc(256*4);
  _Float16* cs16A  = (_Float16*)alloc(256*2);
  _Float16* csh16A = (_Float16*)alloc(256*2);
  _Float16* cs16B  = (_Float16*)alloc(256*2);
  _Float16* csh16B = (_Float16*)alloc(256*2);

  const int din[4]  = {64, 128, 256, 128};
  const int dto[4]  = {128, 256, 128, 64};
  const size_t aggN = (size_t)NN*256;      // halves per chunk slab
  _Float16* WpL[4];
  PackArgs pa; int pj = 0, poff = 0;
  for(int l = 0; l < 4; l++){
    int nch = din[l]/64;
    WpL[l] = (_Float16*)alloc((size_t)nch*832*dto[l]*2);
    for(int c = 0; c < nch; c++){
      pa.job[pj] = { W[l], WpL[l] + (size_t)c*832*dto[l], din[l], dto[l], c*64, poff };
      poff += 832*dto[l]; pj++;
    }
  }
  pa.total = poff;

  hipMemsetAsync(deg, 0, (size_t)NN*4, stream);
  hipMemsetAsync(dsum, 0, 4, stream);
  hipMemsetAsync(colsumL, 0, 4*256*4, stream);
  hipMemsetAsync(colssL,  0, 4*256*4, stream);

  k_pack_all<<<(pa.total+255)/256, 256, 0, stream>>>(pa);
  k_deg     <<<(NE+255)/256, 256, 0, stream>>>(edst, deg);
  k_logdeg  <<<(NN+255)/256, 256, 0, stream>>>(deg, logdeg, dsum);
  k_scalers <<<(NN+255)/256, 256, 0, stream>>>(logdeg, dsum, amp, att);
  k_scan1   <<<NB, 1024, 0, stream>>>(deg, rowptr, bsum);
  k_scan2   <<<1, 64, 0, stream>>>(bsum);
  k_scan3   <<<(NN+256)/256, 256, 0, stream>>>(rowptr, cursor, bsum);
  k_fill    <<<(NE+255)/256, 256, 0, stream>>>(esrc, edst, cursor, colidx);
  k_cvtx    <<<(NN*64+255)/256, 256, 0, stream>>>(x, act0);
  k_coef_id <<<1, 256, 0, stream>>>(csA, cshA, cs16A, csh16A);

  _Float16* actIn = act0;  _Float16* actOut = act1;
  float *csI = csA, *cshI = cshA, *csO = csB, *cshO = cshB;
  _Float16 *cs16I = cs16A, *csh16I = csh16A, *cs16O = cs16B, *csh16O = csh16B;

  const int NPC = (NN + 31) >> 5;         // node-blocks per chunk

  for(int l = 0; l < 4; l++){
    int d = din[l], o = dto[l];
    int nagg = NPC * (d/64);              // chunk-major grid
    dim3 g(o/64, (NN+127)/128);
    float* csum = colsumL + l*256;
    float* csq  = colssL + l*256;
    switch(d){
      case 64:
        k_agg8c<64><<<nagg, 256, 0, stream>>>(actIn, rowptr, colidx, csI, cshI, aggs, aggN);
        k_mfma_fused<1><<<g, 256, 0, stream>>>(actIn, aggs, amp, att, cs16I, csh16I,
                                               WpL[l], o, bb[l], actOut, csum, csq, aggN);
        break;
      case 128:
        k_agg8c<128><<<nagg, 256, 0, stream>>>(actIn, rowptr, colidx, csI, cshI, aggs, aggN);
        k_mfma_fused<2><<<g, 256, 0, stream>>>(actIn, aggs, amp, att, cs16I, csh16I,
                                               WpL[l], o, bb[l], actOut, csum, csq, aggN);
        break;
      default:
        k_agg8c<256><<<nagg, 256, 0, stream>>>(actIn, rowptr, colidx, csI, cshI, aggs, aggN);
        k_mfma_fused<4><<<g, 256, 0, stream>>>(actIn, aggs, amp, att, cs16I, csh16I,
                                               WpL[l], o, bb[l], actOut, csum, csq, aggN);
        break;
    }
    k_bn_coef<<<1, 256, 0, stream>>>(csum, csq, gm[l], bt[l], o,
                                     csO, cshO, cs16O, csh16O);
    // swap activation and coefficient buffers
    _Float16* ta = actIn; actIn = actOut; actOut = ta;
    float* tf;
    tf = csI;  csI = csO;  csO = tf;
    tf = cshI; cshI = cshO; cshO = tf;
    _Float16* th;
    th = cs16I;  cs16I = cs16O;  cs16O = th;
    th = csh16I; csh16I = csh16O; csh16O = th;
  }
  k_cls<<<(NN*16+255)/256, 256, 0, stream>>>(actIn, csI, cshI, Wc, bc, (float*)d_out);
}